// Round 5
// baseline (640.498 us; speedup 1.0000x reference)
//
#include <hip/hip_runtime.h>
#include <hip/hip_fp16.h>
#include <math.h>

typedef unsigned int uint;
typedef unsigned short ushort;

#define B_ 256
#define T_ 512
#define F_ 378
#define C_ 128
#define H_ 64
#define KPAD 1152   // 3 * 384

using f32x4 = __attribute__((ext_vector_type(4))) float;
using bf16x8 = __attribute__((ext_vector_type(8))) short;

__device__ __forceinline__ ushort f2bf(float f) {
  union { float f; uint u; } c; c.f = f;
  uint r = (c.u + 0x7fffu + ((c.u >> 16) & 1u)) >> 16;
  return (ushort)r;
}
__device__ __forceinline__ float bf2f(ushort u) {
  union { uint u; float f; } c; c.u = ((uint)u) << 16;
  return c.f;
}
__device__ __forceinline__ uint packbf2(float a, float b) {
  return (uint)f2bf(a) | (((uint)f2bf(b)) << 16);
}
__device__ __forceinline__ float2 bfpair(uint u) {
  union { uint u; float f; } a, b;
  a.u = (u & 0xffffu) << 16;
  b.u = u & 0xffff0000u;
  float2 r; r.x = a.f; r.y = b.f; return r;
}

// ---------------- pack conv w -> wbT[c][kk], kk = k*384+f, bf16 ------------
__global__ __launch_bounds__(256) void pack_w_kernel(
    const float* __restrict__ w, ushort* __restrict__ wbT) {
  int i = blockIdx.x * 256 + threadIdx.x;
  if (i >= C_ * KPAD) return;
  int c = i / KPAD, kk = i - c * KPAD;
  int k = kk / 384, f = kk - k * 384;
  float v = (f < F_) ? w[c * (F_ * 3) + f * 3 + k] : 0.f;
  wbT[i] = f2bf(v);
}

// ---- pack w_ih -> wP[dir][g'][128] bf16, g' = 4j+e (gate-interleaved) -----
__global__ __launch_bounds__(256) void pack_wiP_kernel(
    const float* __restrict__ wf, const float* __restrict__ wb,
    ushort* __restrict__ wP) {
  int i = blockIdx.x * 256 + threadIdx.x;  // 2*256*128 = 65536
  int dir = i >> 15, rem = i & 32767;
  int gp = rem >> 7, k = rem & 127;
  int j = gp >> 2, e = gp & 3;
  const float* src = dir ? wb : wf;
  wP[i] = f2bf(src[(e * 64 + j) * 128 + k]);
}

// ---- pack w_hh -> whhP[dir][g'][64] bf16, interleaved ---------------------
__global__ __launch_bounds__(256) void pack_whhP_kernel(
    const float* __restrict__ wf, const float* __restrict__ wb,
    ushort* __restrict__ whhP) {
  int i = blockIdx.x * 256 + threadIdx.x;  // 2*256*64 = 32768
  if (i >= 32768) return;
  int dir = i >> 14, rem = i & 16383;
  int gp = rem >> 6, k = rem & 63;
  int j = gp >> 2, e = gp & 3;
  const float* src = dir ? wb : wf;
  whhP[i] = f2bf(src[(e * 64 + j) * 64 + k]);
}

// ---- pack bias -> biasP[dir][g'] fp32, interleaved ------------------------
__global__ __launch_bounds__(256) void pack_biasP_kernel(
    const float* __restrict__ bf, const float* __restrict__ bb,
    float* __restrict__ biasP) {
  int i = blockIdx.x * 256 + threadIdx.x;  // 512
  if (i >= 512) return;
  int dir = i >> 8, gp = i & 255;
  int j = gp >> 2, e = gp & 3;
  const float* src = dir ? bb : bf;
  biasP[i] = src[e * 64 + j];
}

// ---------------- Conv1d as implicit GEMM, bf16 MFMA (unchanged) -----------
__global__ __launch_bounds__(256, 2) void conv_gemm_kernel(
    const float* __restrict__ x, const ushort* __restrict__ wbT,
    const float* __restrict__ bias, ushort* __restrict__ y) {
  __shared__ __align__(16) char xsb[130 * 128];
  __shared__ __align__(16) char bsb[128 * 384];
  const int tid = threadIdx.x;
  const int lane = tid & 63;
  const int wr = (tid >> 7) & 1;
  const int wc = (tid >> 6) & 1;
  const int b = blockIdx.x >> 2;
  const int t0 = (blockIdx.x & 3) << 7;

  f32x4 acc[4][4];
#pragma unroll
  for (int m = 0; m < 4; ++m)
#pragma unroll
    for (int n = 0; n < 4; ++n) acc[m][n] = (f32x4)(0.f);

  for (int fs = 0; fs < 6; ++fs) {
    __syncthreads();
    {
      auto stage_a = [&](int r, int h) {
        const int t = t0 - 1 + r;
        const bool ok = (t >= 0) && (t < T_);
        const float* srow = x + ((long)b * T_ + (ok ? t : 0)) * F_;
        const int fb = fs * 64 + h * 32;
        char* dst = xsb + r * 128;
        const int sw = (r & 7) << 4;
        uint pk[16];
        if (ok && fb + 31 < F_) {
#pragma unroll
          for (int j = 0; j < 16; ++j) {
            float2 v = *(const float2*)(srow + fb + 2 * j);
            pk[j] = packbf2(v.x, v.y);
          }
        } else {
#pragma unroll
          for (int j = 0; j < 16; ++j) {
            const int f = fb + 2 * j;
            float a = (ok && f < F_) ? srow[f] : 0.f;
            float c2 = (ok && f + 1 < F_) ? srow[f + 1] : 0.f;
            pk[j] = packbf2(a, c2);
          }
        }
#pragma unroll
        for (int j = 0; j < 4; ++j) {
          uint4 p = {pk[4 * j], pk[4 * j + 1], pk[4 * j + 2], pk[4 * j + 3]};
          *(uint4*)(dst + ((h * 64 + j * 16) ^ sw)) = p;
        }
      };
      stage_a(tid >> 1, tid & 1);
      if (tid < 4) stage_a(128 + (tid >> 1), tid & 1);
    }
    {
      const int c = tid >> 1, h = tid & 1;
      const ushort* src = wbT + c * KPAD + fs * 64 + h * 32;
      char* drow = bsb + c * 384;
      const int sw = (c & 7) << 4;
#pragma unroll
      for (int k = 0; k < 3; ++k)
#pragma unroll
        for (int j = 0; j < 4; ++j) {
          uint4 v = *(const uint4*)(src + k * 384 + j * 8);
          *(uint4*)(drow + k * 128 + ((h * 64 + j * 16) ^ sw)) = v;
        }
    }
    __syncthreads();

#pragma unroll
    for (int k = 0; k < 3; ++k) {
#pragma unroll
      for (int s = 0; s < 2; ++s) {
        bf16x8 af[4], bfx[4];
        const int ksub = s * 64 + ((lane >> 4) << 4);
#pragma unroll
        for (int m = 0; m < 4; ++m) {
          const int rr = wr * 64 + m * 16 + (lane & 15) + k;
          af[m] = *(const bf16x8*)(xsb + rr * 128 + (ksub ^ ((rr & 7) << 4)));
        }
#pragma unroll
        for (int n = 0; n < 4; ++n) {
          const int c = wc * 64 + n * 16 + (lane & 15);
          bfx[n] =
              *(const bf16x8*)(bsb + c * 384 + k * 128 + (ksub ^ ((c & 7) << 4)));
        }
#pragma unroll
        for (int m = 0; m < 4; ++m)
#pragma unroll
          for (int n = 0; n < 4; ++n)
            acc[m][n] = __builtin_amdgcn_mfma_f32_16x16x32_bf16(
                af[m], bfx[n], acc[m][n], 0, 0, 0);
      }
    }
  }

  __syncthreads();
  float bc[4];
#pragma unroll
  for (int n = 0; n < 4; ++n) bc[n] = bias[wc * 64 + n * 16 + (lane & 15)];
#pragma unroll
  for (int m = 0; m < 4; ++m) {
#pragma unroll
    for (int n = 0; n < 4; ++n) {
      const int col = wc * 64 + n * 16 + (lane & 15);
#pragma unroll
      for (int r = 0; r < 4; ++r) {
        const int row = wr * 64 + m * 16 + ((lane >> 4) << 2) + r;
        float v = acc[m][n][r] + bc[n];
        v = v > 0.f ? v : 0.f;
        *(ushort*)(bsb + row * 256 + ((col * 2) ^ ((row & 7) << 4))) = f2bf(v);
      }
    }
  }
  __syncthreads();
  const int w = tid >> 6;
#pragma unroll
  for (int p = 0; p < 8; ++p) {
    const int rowb = p * 16 + w * 4 + (lane >> 4);
    const int colb = (lane & 15) * 16;
    uint4 v = *(const uint4*)(bsb + rowb * 256 + (colb ^ ((rowb & 7) << 4)));
    *(uint4*)((char*)(y + ((long)b * T_ + t0 + rowb) * 128) + colb) = v;
  }
}

// ---------------- xg GEMM: xgP[dir][b*T+t][256] fp16 = y @ wP^T + bias -----
// M = B*T (tiles 128), N = 128 per block (4 n-blocks: dir x half), K = 128.
__global__ __launch_bounds__(256, 2) void xg_gemm_kernel(
    const ushort* __restrict__ y, const ushort* __restrict__ wP,
    const float* __restrict__ biasP, ushort* __restrict__ xgP) {
  __shared__ __align__(16) char xsb[128 * 256];  // A: 128 m x 128 k bf16
  __shared__ __align__(16) char bsb[128 * 256];  // B: 128 g' x 128 k bf16
  const int tid = threadIdx.x;
  const int lane = tid & 63;
  const int wr = (tid >> 7) & 1;
  const int wc = (tid >> 6) & 1;
  const int mb = blockIdx.x >> 2;
  const int nb = blockIdx.x & 3;
  const int m0 = mb << 7;
  const int dirBT = (nb >> 1) * (B_ * T_);
  const int gbase = (nb >> 1) * 256 + (nb & 1) * 128;

  // stage A and B (128 rows x 256B each), swizzled
  {
    const int r = tid >> 1, h = tid & 1;
    const int sw = (r & 7) << 4;
    const ushort* sa = y + ((long)(m0 + r)) * 128 + h * 64;
    const ushort* sb = wP + (gbase + r) * 128 + h * 64;
    char* da = xsb + r * 256;
    char* db = bsb + r * 256;
#pragma unroll
    for (int j = 0; j < 8; ++j) {
      uint4 va = *(const uint4*)(sa + 8 * j);
      uint4 vb = *(const uint4*)(sb + 8 * j);
      const int inner = (h * 128 + j * 16) ^ sw;
      *(uint4*)(da + inner) = va;
      *(uint4*)(db + inner) = vb;
    }
  }
  __syncthreads();

  f32x4 acc[4][4];
#pragma unroll
  for (int m = 0; m < 4; ++m)
#pragma unroll
    for (int n = 0; n < 4; ++n) acc[m][n] = (f32x4)(0.f);

#pragma unroll
  for (int ks = 0; ks < 4; ++ks) {
    bf16x8 af[4], bfx[4];
    const int ksub = ks * 64 + ((lane >> 4) << 4);
#pragma unroll
    for (int m = 0; m < 4; ++m) {
      const int rr = wr * 64 + m * 16 + (lane & 15);
      af[m] = *(const bf16x8*)(xsb + rr * 256 + (ksub ^ ((rr & 7) << 4)));
    }
#pragma unroll
    for (int n = 0; n < 4; ++n) {
      const int c = wc * 64 + n * 16 + (lane & 15);
      bfx[n] = *(const bf16x8*)(bsb + c * 256 + (ksub ^ ((c & 7) << 4)));
    }
#pragma unroll
    for (int m = 0; m < 4; ++m)
#pragma unroll
      for (int n = 0; n < 4; ++n)
        acc[m][n] = __builtin_amdgcn_mfma_f32_16x16x32_bf16(af[m], bfx[n],
                                                            acc[m][n], 0, 0, 0);
  }

  // epilogue: +bias, fp16, transpose in LDS (reuse bsb), coalesced store
  __syncthreads();
  float bc[4];
#pragma unroll
  for (int n = 0; n < 4; ++n)
    bc[n] = biasP[gbase + wc * 64 + n * 16 + (lane & 15)];
#pragma unroll
  for (int m = 0; m < 4; ++m) {
#pragma unroll
    for (int n = 0; n < 4; ++n) {
      const int col = wc * 64 + n * 16 + (lane & 15);
#pragma unroll
      for (int r = 0; r < 4; ++r) {
        const int row = wr * 64 + m * 16 + ((lane >> 4) << 2) + r;
        float v = acc[m][n][r] + bc[n];
        __half hv = __float2half(v);
        *(ushort*)(bsb + row * 256 + ((col * 2) ^ ((row & 7) << 4))) =
            *(ushort*)&hv;
      }
    }
  }
  __syncthreads();
  const int w = tid >> 6;
#pragma unroll
  for (int p = 0; p < 8; ++p) {
    const int rowb = p * 16 + w * 4 + (lane >> 4);
    const int colb = (lane & 15) * 16;
    uint4 v = *(const uint4*)(bsb + rowb * 256 + (colb ^ ((rowb & 7) << 4)));
    *(uint4*)((char*)xgP + ((long)(dirBT + m0 + rowb)) * 512 + (nb & 1) * 256 +
              colb) = v;
  }
}

// ---------------- LSTM scan: 16 seqs/block, MFMA recurrence ----------------
// 32 blocks (16 b-groups x 2 dirs), 512 threads = 8 waves.
// G[256g' x 16s] = whhP(A, pinned) @ h^T(B, hi+lo bf16 from LDS).
// Lane (s=l&15, q=l>>4) in wave w owns units j = 8w+q and 8w+4+q:
// acc regs r=0..3 are exactly (i,f,g,o) of that unit. One s_barrier/step.
__device__ __forceinline__ float sigm(float v) {
  return 1.f / (1.f + __expf(-v));
}
__device__ __forceinline__ float tanh_fast(float v) {
  return 2.f / (1.f + __expf(-2.f * v)) - 1.f;
}

#define LSTM_STEP(T, XR0, XR1)                                                \
  do {                                                                        \
    const int p_ = (T) & 1;                                                   \
    uint2 cur0 = XR0, cur1 = XR1;                                             \
    {                                                                         \
      int tp = (T) + 2;                                                       \
      if (tp > T_ - 1) tp = T_ - 1;                                           \
      const int ttp = dir ? (T_ - 1 - tp) : tp;                               \
      const ushort* xr = xgP + (xgrow + ttp) * 256;                           \
      XR0 = *(const uint2*)(xr + xc0);                                        \
      XR1 = *(const uint2*)(xr + xc1);                                        \
    }                                                                         \
    bf16x8 bh0, bh1, bl0, bl1;                                                \
    {                                                                         \
      const char* hb = (const char*)(&hhi[p_][0]);                            \
      const char* lb = (const char*)(&hlo[p_][0]);                            \
      const int a0 = s * 128 + (((lane >> 4) * 16) ^ hsw);                    \
      const int a1 = s * 128 + ((64 + (lane >> 4) * 16) ^ hsw);               \
      bh0 = *(const bf16x8*)(hb + a0);                                        \
      bh1 = *(const bf16x8*)(hb + a1);                                        \
      bl0 = *(const bf16x8*)(lb + a0);                                        \
      bl1 = *(const bf16x8*)(lb + a1);                                        \
    }                                                                         \
    f32x4 ac0 = (f32x4)(0.f), ac1 = (f32x4)(0.f);                             \
    ac0 = __builtin_amdgcn_mfma_f32_16x16x32_bf16(afr00, bh0, ac0, 0, 0, 0);  \
    ac1 = __builtin_amdgcn_mfma_f32_16x16x32_bf16(afr10, bh0, ac1, 0, 0, 0);  \
    ac0 = __builtin_amdgcn_mfma_f32_16x16x32_bf16(afr01, bh1, ac0, 0, 0, 0);  \
    ac1 = __builtin_amdgcn_mfma_f32_16x16x32_bf16(afr11, bh1, ac1, 0, 0, 0);  \
    ac0 = __builtin_amdgcn_mfma_f32_16x16x32_bf16(afr00, bl0, ac0, 0, 0, 0);  \
    ac1 = __builtin_amdgcn_mfma_f32_16x16x32_bf16(afr10, bl0, ac1, 0, 0, 0);  \
    ac0 = __builtin_amdgcn_mfma_f32_16x16x32_bf16(afr01, bl1, ac0, 0, 0, 0);  \
    ac1 = __builtin_amdgcn_mfma_f32_16x16x32_bf16(afr11, bl1, ac1, 0, 0, 0);  \
    const int tt_ = dir ? (T_ - 1 - (T)) : (T);                               \
    {                                                                         \
      float2 x01 = __half22float2(*(const __half2*)&cur0.x);                  \
      float2 x23 = __half22float2(*(const __half2*)&cur0.y);                  \
      float pi = ac0[0] + x01.x, pf = ac0[1] + x01.y;                         \
      float pg = ac0[2] + x23.x, po = ac0[3] + x23.y;                         \
      c0 = sigm(pf) * c0 + sigm(pi) * tanh_fast(pg);                          \
      float hv = sigm(po) * tanh_fast(c0);                                    \
      ushort hi = f2bf(hv);                                                   \
      ushort lo = f2bf(hv - bf2f(hi));                                        \
      hout[obase + tt_ * 128 + 8 * wv + (lane >> 4)] = hi;                    \
      *(ushort*)((char*)(&hhi[1 - p_][0]) + wb0) = hi;                        \
      *(ushort*)((char*)(&hlo[1 - p_][0]) + wb0) = lo;                        \
    }                                                                         \
    {                                                                         \
      float2 x01 = __half22float2(*(const __half2*)&cur1.x);                  \
      float2 x23 = __half22float2(*(const __half2*)&cur1.y);                  \
      float pi = ac1[0] + x01.x, pf = ac1[1] + x01.y;                         \
      float pg = ac1[2] + x23.x, po = ac1[3] + x23.y;                         \
      c1 = sigm(pf) * c1 + sigm(pi) * tanh_fast(pg);                          \
      float hv = sigm(po) * tanh_fast(c1);                                    \
      ushort hi = f2bf(hv);                                                   \
      ushort lo = f2bf(hv - bf2f(hi));                                        \
      hout[obase + tt_ * 128 + 8 * wv + 4 + (lane >> 4)] = hi;                \
      *(ushort*)((char*)(&hhi[1 - p_][0]) + wb1) = hi;                        \
      *(ushort*)((char*)(&hlo[1 - p_][0]) + wb1) = lo;                        \
    }                                                                         \
    asm volatile("s_waitcnt lgkmcnt(0)" ::: "memory");                        \
    __builtin_amdgcn_sched_barrier(0);                                        \
    __builtin_amdgcn_s_barrier();                                             \
    __builtin_amdgcn_sched_barrier(0);                                        \
  } while (0)

__global__ __launch_bounds__(512, 1) void lstm_seq_kernel(
    const ushort* __restrict__ whhP, const ushort* __restrict__ xgP,
    ushort* __restrict__ hout) {
  const int dir = blockIdx.x >> 4;
  const int bg = blockIdx.x & 15;
  const int tid = threadIdx.x;
  const int lane = tid & 63;
  const int wv = tid >> 6;  // wave 0..7
  const int s = lane & 15;

  __shared__ __align__(16) ushort hhi[2][1024];
  __shared__ __align__(16) ushort hlo[2][1024];
  for (int i = tid; i < 1024; i += 512) {
    hhi[0][i] = 0;
    hlo[0][i] = 0;
  }

  // pinned A-frags: whhP rows g' = 32w+16mi+s, k = ks*32 + (l>>4)*8
  bf16x8 afr00, afr01, afr10, afr11;
  {
    const ushort* base = whhP + (long)dir * 256 * 64;
    const int kof = (lane >> 4) * 8;
    afr00 = *(const bf16x8*)(base + (32 * wv + s) * 64 + kof);
    afr01 = *(const bf16x8*)(base + (32 * wv + s) * 64 + 32 + kof);
    afr10 = *(const bf16x8*)(base + (32 * wv + 16 + s) * 64 + kof);
    afr11 = *(const bf16x8*)(base + (32 * wv + 16 + s) * 64 + 32 + kof);
  }

  const int b = bg * 16 + s;
  const long xgrow = ((long)dir * B_ + b) * T_;
  const int xc0 = 32 * wv + 4 * (lane >> 4);
  const int xc1 = 32 * wv + 16 + 4 * (lane >> 4);
  const long obase = (long)b * T_ * 128 + dir * 64;
  const int hsw = (s & 7) << 4;
  const int wb0 = s * 128 + ((16 * wv + 2 * (lane >> 4)) ^ hsw);
  const int wb1 = s * 128 + ((16 * wv + 8 + 2 * (lane >> 4)) ^ hsw);

  float c0 = 0.f, c1 = 0.f;

  // prefetch xg for t=0,1
  uint2 xa0, xa1, xb0, xb1;
  {
    const int tt0 = dir ? (T_ - 1) : 0;
    const ushort* xr = xgP + (xgrow + tt0) * 256;
    xa0 = *(const uint2*)(xr + xc0);
    xa1 = *(const uint2*)(xr + xc1);
  }
  {
    const int tt1 = dir ? (T_ - 2) : 1;
    const ushort* xr = xgP + (xgrow + tt1) * 256;
    xb0 = *(const uint2*)(xr + xc0);
    xb1 = *(const uint2*)(xr + xc1);
  }
  __syncthreads();

  for (int it = 0; it < T_ / 2; ++it) {
    LSTM_STEP(2 * it, xa0, xa1);
    LSTM_STEP(2 * it + 1, xb0, xb1);
  }
}

// ---------------- Attention pool + LayerNorm + FC (bf16 hio) ---------------
__global__ __launch_bounds__(256) void head_kernel(
    const ushort* __restrict__ hio, const float* __restrict__ attn_w,
    const float* __restrict__ attn_b, const float* __restrict__ ln_g,
    const float* __restrict__ ln_b, const float* __restrict__ fc_w,
    const float* __restrict__ fc_b, float* __restrict__ res) {
  const int b = blockIdx.x;
  const int tid = threadIdx.x;
  __shared__ __align__(16) float aw[128];
  __shared__ float l[T_];
  __shared__ float red[16];
  __shared__ float pp[2][128];
  __shared__ float normed[128];
  if (tid < 128) aw[tid] = attn_w[tid];
  __syncthreads();
  const float ab = attn_b[0];

  for (int t = tid; t < T_; t += 256) {
    const ushort* row = hio + ((long)b * T_ + t) * 128;
    float a = ab;
#pragma unroll
    for (int d = 0; d < 128; d += 8) {
      uint4 v = *(const uint4*)(row + d);
      float2 p0 = bfpair(v.x), p1 = bfpair(v.y);
      float2 p2 = bfpair(v.z), p3 = bfpair(v.w);
      a += p0.x * aw[d] + p0.y * aw[d + 1] + p1.x * aw[d + 2] +
           p1.y * aw[d + 3] + p2.x * aw[d + 4] + p2.y * aw[d + 5] +
           p3.x * aw[d + 6] + p3.y * aw[d + 7];
    }
    l[t] = a;
  }
  __syncthreads();

  float v0 = l[tid], v1 = l[tid + 256];
  float m = fmaxf(v0, v1);
#pragma unroll
  for (int off = 32; off >= 1; off >>= 1) m = fmaxf(m, __shfl_xor(m, off));
  if ((tid & 63) == 0) red[tid >> 6] = m;
  __syncthreads();
  m = fmaxf(fmaxf(red[0], red[1]), fmaxf(red[2], red[3]));
  float e0 = __expf(v0 - m), e1 = __expf(v1 - m);
  float ssum = e0 + e1;
#pragma unroll
  for (int off = 32; off >= 1; off >>= 1) ssum += __shfl_xor(ssum, off);
  if ((tid & 63) == 0) red[4 + (tid >> 6)] = ssum;
  __syncthreads();
  float inv = 1.f / (red[4] + red[5] + red[6] + red[7]);
  l[tid] = e0 * inv;
  l[tid + 256] = e1 * inv;
  __syncthreads();

  const int d = tid & 127, half = tid >> 7;
  float p = 0.f;
  for (int t = half * 256; t < half * 256 + 256; ++t)
    p += l[t] * bf2f(hio[((long)b * T_ + t) * 128 + d]);
  pp[half][d] = p;
  __syncthreads();

  if (tid < 128) {
    float pv = pp[0][tid] + pp[1][tid];
    float s1 = pv, s2 = pv * pv;
#pragma unroll
    for (int off = 32; off >= 1; off >>= 1) {
      s1 += __shfl_xor(s1, off);
      s2 += __shfl_xor(s2, off);
    }
    if ((tid & 63) == 0) {
      red[8 + (tid >> 6) * 2] = s1;
      red[9 + (tid >> 6) * 2] = s2;
    }
  }
  __syncthreads();
  if (tid < 128) {
    float s1 = red[8] + red[10], s2 = red[9] + red[11];
    float mu = s1 * (1.f / 128.f);
    float var = s2 * (1.f / 128.f) - mu * mu;
    float rinv = rsqrtf(var + 1e-5f);
    float pv = pp[0][tid] + pp[1][tid];
    normed[tid] = (pv - mu) * rinv * ln_g[tid] + ln_b[tid];
  }
  __syncthreads();

  if (tid < 2) {
    float a = fc_b[tid];
    for (int d2 = 0; d2 < 128; ++d2) a += normed[d2] * fc_w[tid * 128 + d2];
    res[b * 2 + tid] = a;
  }
}

extern "C" void kernel_launch(void* const* d_in, const int* in_sizes, int n_in,
                              void* d_out, int out_size, void* d_ws,
                              size_t ws_size, hipStream_t stream) {
  const float* x = (const float*)d_in[0];
  const float* conv_w = (const float*)d_in[1];
  const float* conv_b = (const float*)d_in[2];
  const float* w_ih_f = (const float*)d_in[3];
  const float* w_hh_f = (const float*)d_in[4];
  const float* b_f = (const float*)d_in[5];
  const float* w_ih_b = (const float*)d_in[6];
  const float* w_hh_b = (const float*)d_in[7];
  const float* b_b = (const float*)d_in[8];
  const float* attn_w = (const float*)d_in[9];
  const float* attn_b = (const float*)d_in[10];
  const float* ln_g = (const float*)d_in[11];
  const float* ln_b = (const float*)d_in[12];
  const float* fc_w = (const float*)d_in[13];
  const float* fc_b = (const float*)d_in[14];
  float* res = (float*)d_out;

  // ws layout (~161 MiB):
  char* ws = (char*)d_ws;
  ushort* wbT = (ushort*)ws;                      // 294,912 B
  ushort* wP = (ushort*)(ws + 0x60000);           // 131,072 B
  ushort* whhP = (ushort*)(ws + 0x80000);         // 65,536 B
  float* biasP = (float*)(ws + 0x90000);          // 2,048 B
  ushort* xgP = (ushort*)(ws + 0x100000);         // 134,217,728 B
  ushort* y = (ushort*)(ws + 0x100000 + 134217728);  // 33,554,432 B
  ushort* hout = y;  // aliases y: y is dead after xg_gemm

  pack_w_kernel<<<576, 256, 0, stream>>>(conv_w, wbT);
  pack_wiP_kernel<<<256, 256, 0, stream>>>(w_ih_f, w_ih_b, wP);
  pack_whhP_kernel<<<128, 256, 0, stream>>>(w_hh_f, w_hh_b, whhP);
  pack_biasP_kernel<<<2, 256, 0, stream>>>(b_f, b_b, biasP);
  conv_gemm_kernel<<<B_ * (T_ / 128), 256, 0, stream>>>(x, wbT, conv_b, y);
  xg_gemm_kernel<<<(B_ * T_ / 128) * 4, 256, 0, stream>>>(y, wP, biasP, xgP);
  lstm_seq_kernel<<<32, 512, 0, stream>>>(whhP, xgP, hout);
  head_kernel<<<B_, 256, 0, stream>>>(hout, attn_w, attn_b, ln_g, ln_b, fc_w,
                                      fc_b, res);
}

// Round 6
// 558.421 us; speedup vs baseline: 1.1470x; 1.1470x over previous
//
#include <hip/hip_runtime.h>
#include <hip/hip_fp16.h>
#include <math.h>

typedef unsigned int uint;
typedef unsigned short ushort;

#define B_ 256
#define T_ 512
#define F_ 378
#define C_ 128
#define H_ 64
#define KPAD 1152   // 3 * 384

using f32x4 = __attribute__((ext_vector_type(4))) float;
using bf16x8 = __attribute__((ext_vector_type(8))) short;

__device__ __forceinline__ ushort f2bf(float f) {
  union { float f; uint u; } c; c.f = f;
  uint r = (c.u + 0x7fffu + ((c.u >> 16) & 1u)) >> 16;
  return (ushort)r;
}
__device__ __forceinline__ float bf2f(ushort u) {
  union { uint u; float f; } c; c.u = ((uint)u) << 16;
  return c.f;
}
__device__ __forceinline__ uint packbf2(float a, float b) {
  return (uint)f2bf(a) | (((uint)f2bf(b)) << 16);
}
__device__ __forceinline__ float2 bfpair(uint u) {
  union { uint u; float f; } a, b;
  a.u = (u & 0xffffu) << 16;
  b.u = u & 0xffff0000u;
  float2 r; r.x = a.f; r.y = b.f; return r;
}
// fast activations: v_exp_f32 is 2^x; rcp is 1-ulp-ish (fine at bf16 scale)
__device__ __forceinline__ float sigm(float v) {
  return __builtin_amdgcn_rcpf(1.f + __builtin_amdgcn_exp2f(-1.442695041f * v));
}
__device__ __forceinline__ float tanh_fast(float v) {
  return fmaf(-2.f,
              __builtin_amdgcn_rcpf(1.f + __builtin_amdgcn_exp2f(2.885390082f * v)),
              1.f);
}

// ---------------- pack conv w -> wbT[c][kk], kk = k*384+f, bf16 ------------
__global__ __launch_bounds__(256) void pack_w_kernel(
    const float* __restrict__ w, ushort* __restrict__ wbT) {
  int i = blockIdx.x * 256 + threadIdx.x;
  if (i >= C_ * KPAD) return;
  int c = i / KPAD, kk = i - c * KPAD;
  int k = kk / 384, f = kk - k * 384;
  float v = (f < F_) ? w[c * (F_ * 3) + f * 3 + k] : 0.f;
  wbT[i] = f2bf(v);
}

// ---- pack w_ih -> wP[dir][g''][128] bf16; g'' = w*64+q*16+n*4+e ----------
// maps to original gate-row e*64 + (16w+4q+n). Lane (s,q) of wave w in the
// scan reads 16 contiguous fp16 xg values = its 4 units x 4 gates.
__global__ __launch_bounds__(256) void pack_wiP_kernel(
    const float* __restrict__ wf, const float* __restrict__ wb,
    ushort* __restrict__ wP) {
  int i = blockIdx.x * 256 + threadIdx.x;  // 2*256*128 = 65536
  int dir = i >> 15, rem = i & 32767;
  int gp = rem >> 7, k = rem & 127;
  int e = gp & 3, n = (gp >> 2) & 3, q = (gp >> 4) & 3, w = gp >> 6;
  int u = 16 * w + 4 * q + n;
  const float* src = dir ? wb : wf;
  wP[i] = f2bf(src[(e * 64 + u) * 128 + k]);
}

// ---- pack w_hh -> whhP[dir][r][64] bf16; r = 64w+16n+4q+e -----------------
// output row m=4q+e of MFMA tile n (wave w) = gate e of unit 16w+4q+n.
__global__ __launch_bounds__(256) void pack_whhP_kernel(
    const float* __restrict__ wf, const float* __restrict__ wb,
    ushort* __restrict__ whhP) {
  int i = blockIdx.x * 256 + threadIdx.x;  // 2*256*64 = 32768
  if (i >= 32768) return;
  int dir = i >> 14, rem = i & 16383;
  int r = rem >> 6, k = rem & 63;
  int e = r & 3, q = (r >> 2) & 3, n = (r >> 4) & 3, w = r >> 6;
  int u = 16 * w + 4 * q + n;
  const float* src = dir ? wb : wf;
  whhP[i] = f2bf(src[(e * 64 + u) * 64 + k]);
}

// ---- pack bias -> biasP[dir][g''] fp32 (same order as wP) -----------------
__global__ __launch_bounds__(256) void pack_biasP_kernel(
    const float* __restrict__ bf, const float* __restrict__ bb,
    float* __restrict__ biasP) {
  int i = blockIdx.x * 256 + threadIdx.x;  // 512
  if (i >= 512) return;
  int dir = i >> 8, gp = i & 255;
  int e = gp & 3, n = (gp >> 2) & 3, q = (gp >> 4) & 3, w = gp >> 6;
  int u = 16 * w + 4 * q + n;
  const float* src = dir ? bb : bf;
  biasP[i] = src[e * 64 + u];
}

// ---------------- Conv1d as implicit GEMM, bf16 MFMA (unchanged) -----------
__global__ __launch_bounds__(256, 2) void conv_gemm_kernel(
    const float* __restrict__ x, const ushort* __restrict__ wbT,
    const float* __restrict__ bias, ushort* __restrict__ y) {
  __shared__ __align__(16) char xsb[130 * 128];
  __shared__ __align__(16) char bsb[128 * 384];
  const int tid = threadIdx.x;
  const int lane = tid & 63;
  const int wr = (tid >> 7) & 1;
  const int wc = (tid >> 6) & 1;
  const int b = blockIdx.x >> 2;
  const int t0 = (blockIdx.x & 3) << 7;

  f32x4 acc[4][4];
#pragma unroll
  for (int m = 0; m < 4; ++m)
#pragma unroll
    for (int n = 0; n < 4; ++n) acc[m][n] = (f32x4)(0.f);

  for (int fs = 0; fs < 6; ++fs) {
    __syncthreads();
    {
      auto stage_a = [&](int r, int h) {
        const int t = t0 - 1 + r;
        const bool ok = (t >= 0) && (t < T_);
        const float* srow = x + ((long)b * T_ + (ok ? t : 0)) * F_;
        const int fb = fs * 64 + h * 32;
        char* dst = xsb + r * 128;
        const int sw = (r & 7) << 4;
        uint pk[16];
        if (ok && fb + 31 < F_) {
#pragma unroll
          for (int j = 0; j < 16; ++j) {
            float2 v = *(const float2*)(srow + fb + 2 * j);
            pk[j] = packbf2(v.x, v.y);
          }
        } else {
#pragma unroll
          for (int j = 0; j < 16; ++j) {
            const int f = fb + 2 * j;
            float a = (ok && f < F_) ? srow[f] : 0.f;
            float c2 = (ok && f + 1 < F_) ? srow[f + 1] : 0.f;
            pk[j] = packbf2(a, c2);
          }
        }
#pragma unroll
        for (int j = 0; j < 4; ++j) {
          uint4 p = {pk[4 * j], pk[4 * j + 1], pk[4 * j + 2], pk[4 * j + 3]};
          *(uint4*)(dst + ((h * 64 + j * 16) ^ sw)) = p;
        }
      };
      stage_a(tid >> 1, tid & 1);
      if (tid < 4) stage_a(128 + (tid >> 1), tid & 1);
    }
    {
      const int c = tid >> 1, h = tid & 1;
      const ushort* src = wbT + c * KPAD + fs * 64 + h * 32;
      char* drow = bsb + c * 384;
      const int sw = (c & 7) << 4;
#pragma unroll
      for (int k = 0; k < 3; ++k)
#pragma unroll
        for (int j = 0; j < 4; ++j) {
          uint4 v = *(const uint4*)(src + k * 384 + j * 8);
          *(uint4*)(drow + k * 128 + ((h * 64 + j * 16) ^ sw)) = v;
        }
    }
    __syncthreads();

#pragma unroll
    for (int k = 0; k < 3; ++k) {
#pragma unroll
      for (int s = 0; s < 2; ++s) {
        bf16x8 af[4], bfx[4];
        const int ksub = s * 64 + ((lane >> 4) << 4);
#pragma unroll
        for (int m = 0; m < 4; ++m) {
          const int rr = wr * 64 + m * 16 + (lane & 15) + k;
          af[m] = *(const bf16x8*)(xsb + rr * 128 + (ksub ^ ((rr & 7) << 4)));
        }
#pragma unroll
        for (int n = 0; n < 4; ++n) {
          const int c = wc * 64 + n * 16 + (lane & 15);
          bfx[n] =
              *(const bf16x8*)(bsb + c * 384 + k * 128 + (ksub ^ ((c & 7) << 4)));
        }
#pragma unroll
        for (int m = 0; m < 4; ++m)
#pragma unroll
          for (int n = 0; n < 4; ++n)
            acc[m][n] = __builtin_amdgcn_mfma_f32_16x16x32_bf16(
                af[m], bfx[n], acc[m][n], 0, 0, 0);
      }
    }
  }

  __syncthreads();
  float bc[4];
#pragma unroll
  for (int n = 0; n < 4; ++n) bc[n] = bias[wc * 64 + n * 16 + (lane & 15)];
#pragma unroll
  for (int m = 0; m < 4; ++m) {
#pragma unroll
    for (int n = 0; n < 4; ++n) {
      const int col = wc * 64 + n * 16 + (lane & 15);
#pragma unroll
      for (int r = 0; r < 4; ++r) {
        const int row = wr * 64 + m * 16 + ((lane >> 4) << 2) + r;
        float v = acc[m][n][r] + bc[n];
        v = v > 0.f ? v : 0.f;
        *(ushort*)(bsb + row * 256 + ((col * 2) ^ ((row & 7) << 4))) = f2bf(v);
      }
    }
  }
  __syncthreads();
  const int w = tid >> 6;
#pragma unroll
  for (int p = 0; p < 8; ++p) {
    const int rowb = p * 16 + w * 4 + (lane >> 4);
    const int colb = (lane & 15) * 16;
    uint4 v = *(const uint4*)(bsb + rowb * 256 + (colb ^ ((rowb & 7) << 4)));
    *(uint4*)((char*)(y + ((long)b * T_ + t0 + rowb) * 128) + colb) = v;
  }
}

// ---------------- xg GEMM: xgP[dir][b*T+t][256] fp16 = y @ wP^T + bias -----
__global__ __launch_bounds__(256, 2) void xg_gemm_kernel(
    const ushort* __restrict__ y, const ushort* __restrict__ wP,
    const float* __restrict__ biasP, ushort* __restrict__ xgP) {
  __shared__ __align__(16) char xsb[128 * 256];
  __shared__ __align__(16) char bsb[128 * 256];
  const int tid = threadIdx.x;
  const int lane = tid & 63;
  const int wr = (tid >> 7) & 1;
  const int wc = (tid >> 6) & 1;
  const int mb = blockIdx.x >> 2;
  const int nb = blockIdx.x & 3;
  const int m0 = mb << 7;
  const int dirBT = (nb >> 1) * (B_ * T_);
  const int gbase = (nb >> 1) * 256 + (nb & 1) * 128;

  {
    const int r = tid >> 1, h = tid & 1;
    const int sw = (r & 7) << 4;
    const ushort* sa = y + ((long)(m0 + r)) * 128 + h * 64;
    const ushort* sb = wP + (gbase + r) * 128 + h * 64;
    char* da = xsb + r * 256;
    char* db = bsb + r * 256;
#pragma unroll
    for (int j = 0; j < 8; ++j) {
      uint4 va = *(const uint4*)(sa + 8 * j);
      uint4 vb = *(const uint4*)(sb + 8 * j);
      const int inner = (h * 128 + j * 16) ^ sw;
      *(uint4*)(da + inner) = va;
      *(uint4*)(db + inner) = vb;
    }
  }
  __syncthreads();

  f32x4 acc[4][4];
#pragma unroll
  for (int m = 0; m < 4; ++m)
#pragma unroll
    for (int n = 0; n < 4; ++n) acc[m][n] = (f32x4)(0.f);

#pragma unroll
  for (int ks = 0; ks < 4; ++ks) {
    bf16x8 af[4], bfx[4];
    const int ksub = ks * 64 + ((lane >> 4) << 4);
#pragma unroll
    for (int m = 0; m < 4; ++m) {
      const int rr = wr * 64 + m * 16 + (lane & 15);
      af[m] = *(const bf16x8*)(xsb + rr * 256 + (ksub ^ ((rr & 7) << 4)));
    }
#pragma unroll
    for (int n = 0; n < 4; ++n) {
      const int c = wc * 64 + n * 16 + (lane & 15);
      bfx[n] = *(const bf16x8*)(bsb + c * 256 + (ksub ^ ((c & 7) << 4)));
    }
#pragma unroll
    for (int m = 0; m < 4; ++m)
#pragma unroll
      for (int n = 0; n < 4; ++n)
        acc[m][n] = __builtin_amdgcn_mfma_f32_16x16x32_bf16(af[m], bfx[n],
                                                            acc[m][n], 0, 0, 0);
  }

  __syncthreads();
  float bc[4];
#pragma unroll
  for (int n = 0; n < 4; ++n)
    bc[n] = biasP[gbase + wc * 64 + n * 16 + (lane & 15)];
#pragma unroll
  for (int m = 0; m < 4; ++m) {
#pragma unroll
    for (int n = 0; n < 4; ++n) {
      const int col = wc * 64 + n * 16 + (lane & 15);
#pragma unroll
      for (int r = 0; r < 4; ++r) {
        const int row = wr * 64 + m * 16 + ((lane >> 4) << 2) + r;
        float v = acc[m][n][r] + bc[n];
        __half hv = __float2half(v);
        *(ushort*)(bsb + row * 256 + ((col * 2) ^ ((row & 7) << 4))) =
            *(ushort*)&hv;
      }
    }
  }
  __syncthreads();
  const int w = tid >> 6;
#pragma unroll
  for (int p = 0; p < 8; ++p) {
    const int rowb = p * 16 + w * 4 + (lane >> 4);
    const int colb = (lane & 15) * 16;
    uint4 v = *(const uint4*)(bsb + rowb * 256 + (colb ^ ((rowb & 7) << 4)));
    *(uint4*)((char*)xgP + ((long)(dirBT + m0 + rowb)) * 512 + (nb & 1) * 256 +
              colb) = v;
  }
}

// ---------------- LSTM scan: 16 seqs/block, 4 waves, MFMA recurrence -------
// 32 blocks (dir x 16 bgroups), 256 threads. Wave w owns g'-rows
// [64w,64w+64) = 4 MFMA tiles; lane (s=l&15, q=l>>4) owns units
// u = 16w+4q+{0..3} (contiguous -> b64 h writes) for seq s.
// h feedback: hi+lo bf16 split (~fp32 accurate) in double-buffered LDS.
// No global stores in the loop: h staged in LDS, flushed every 16 steps.
#define LSTM_STEP(T, XA, XB)                                                   \
  do {                                                                         \
    const int t_ = (T);                                                        \
    const int p_ = t_ & 1;                                                     \
    const uint4 curA = XA, curB = XB;                                          \
    {                                                                          \
      int tp = t_ + 2;                                                         \
      if (tp > T_ - 1) tp = T_ - 1;                                            \
      const int ttp = dir ? (T_ - 1 - tp) : tp;                                \
      const char* xr = (const char*)xgP + (xgrow + ttp) * 512 + cOff;          \
      XA = *(const uint4*)xr;                                                  \
      XB = *(const uint4*)(xr + 16);                                           \
    }                                                                          \
    bf16x8 bh0, bh1, bl0, bl1;                                                 \
    {                                                                          \
      const char* hb = (const char*)hhi + p_ * 2048;                           \
      const char* lb = (const char*)hlo + p_ * 2048;                           \
      bh0 = *(const bf16x8*)(hb + a0b);                                        \
      bh1 = *(const bf16x8*)(hb + a1b);                                        \
      bl0 = *(const bf16x8*)(lb + a0b);                                        \
      bl1 = *(const bf16x8*)(lb + a1b);                                        \
    }                                                                          \
    f32x4 acH[4], acL[4];                                                      \
    _Pragma("unroll") for (int n = 0; n < 4; ++n) {                            \
      acH[n] = __builtin_amdgcn_mfma_f32_16x16x32_bf16(afA[n], bh0,            \
                                                       (f32x4)(0.f), 0, 0, 0); \
      acL[n] = __builtin_amdgcn_mfma_f32_16x16x32_bf16(afA[n], bl0,            \
                                                       (f32x4)(0.f), 0, 0, 0); \
    }                                                                          \
    _Pragma("unroll") for (int n = 0; n < 4; ++n) {                            \
      acH[n] =                                                                 \
          __builtin_amdgcn_mfma_f32_16x16x32_bf16(afB[n], bh1, acH[n], 0, 0, 0); \
      acL[n] =                                                                 \
          __builtin_amdgcn_mfma_f32_16x16x32_bf16(afB[n], bl1, acL[n], 0, 0, 0); \
    }                                                                          \
    ushort hiu[4];                                                             \
    float hv[4];                                                               \
    _Pragma("unroll") for (int n = 0; n < 4; ++n) {                            \
      const uint lo32 = (n & 1) ? ((n & 2) ? curB.z : curA.z)                  \
                                : ((n & 2) ? curB.x : curA.x);                 \
      const uint hi32 = (n & 1) ? ((n & 2) ? curB.w : curA.w)                  \
                                : ((n & 2) ? curB.y : curA.y);                 \
      float2 x01 = __half22float2(*(const __half2*)&lo32);                     \
      float2 x23 = __half22float2(*(const __half2*)&hi32);                     \
      float pi = acH[n][0] + acL[n][0] + x01.x;                                \
      float pf = acH[n][1] + acL[n][1] + x01.y;                                \
      float pg = acH[n][2] + acL[n][2] + x23.x;                                \
      float po = acH[n][3] + acL[n][3] + x23.y;                                \
      cst[n] = sigm(pf) * cst[n] + sigm(pi) * tanh_fast(pg);                   \
      hv[n] = sigm(po) * tanh_fast(cst[n]);                                    \
      hiu[n] = f2bf(hv[n]);                                                    \
    }                                                                          \
    {                                                                          \
      uint2 HV, LV;                                                            \
      HV.x = (uint)hiu[0] | ((uint)hiu[1] << 16);                              \
      HV.y = (uint)hiu[2] | ((uint)hiu[3] << 16);                              \
      LV.x = (uint)f2bf(hv[0] - bf2f(hiu[0])) |                                \
             ((uint)f2bf(hv[1] - bf2f(hiu[1])) << 16);                         \
      LV.y = (uint)f2bf(hv[2] - bf2f(hiu[2])) |                                \
             ((uint)f2bf(hv[3] - bf2f(hiu[3])) << 16);                         \
      *(uint2*)((char*)hhi + (1 - p_) * 2048 + wbb) = HV;                      \
      *(uint2*)((char*)hlo + (1 - p_) * 2048 + wbb) = LV;                      \
      *(uint2*)((char*)hstage + ((t_ >> 4) & 1) * 32768 + (t_ & 15) * 2048 +   \
                wbb) = HV;                                                     \
    }                                                                          \
    asm volatile("s_waitcnt lgkmcnt(0)" ::: "memory");                         \
    __builtin_amdgcn_sched_barrier(0);                                         \
    __builtin_amdgcn_s_barrier();                                              \
    __builtin_amdgcn_sched_barrier(0);                                         \
    if ((t_ & 15) == 15) {                                                     \
      const int ftl = tid >> 4, fs = tid & 15;                                 \
      const int fsw = (fs & 7) << 4;                                           \
      const char* sb2 = (const char*)hstage + ((t_ >> 4) & 1) * 32768 +        \
                        ftl * 2048 + fs * 128;                                 \
      const int st_ = t_ - 15 + ftl;                                           \
      const int gt = dir ? (T_ - 1 - st_) : st_;                               \
      ushort* dst = hout + ((long)(bg * 16 + fs) * T_ + gt) * 128 + dir * 64;  \
      _Pragma("unroll") for (int j = 0; j < 8; ++j) {                          \
        uint4 v = *(const uint4*)(sb2 + ((j * 16) ^ fsw));                     \
        *(uint4*)(dst + j * 8) = v;                                            \
      }                                                                        \
    }                                                                          \
  } while (0)

__global__ __launch_bounds__(256, 1) void lstm_seq_kernel(
    const ushort* __restrict__ whhP, const ushort* __restrict__ xgP,
    ushort* __restrict__ hout) {
  const int dir = blockIdx.x >> 4;
  const int bg = blockIdx.x & 15;
  const int tid = threadIdx.x;
  const int lane = tid & 63;
  const int w = tid >> 6;   // wave 0..3
  const int s = lane & 15;  // sequence within group
  const int q = lane >> 4;  // quarter

  __shared__ __align__(16) ushort hhi[2 * 1024];        // [2][16s][64u]
  __shared__ __align__(16) ushort hlo[2 * 1024];
  __shared__ __align__(16) ushort hstage[2 * 16 * 16 * 64];  // 64KB

  for (int i = tid; i < 2048; i += 256) {
    hhi[i] = 0;
    hlo[i] = 0;
  }

  // pinned A-frags: whhP rows 64w+16n+s, k chunks [0,32),[32,64)
  bf16x8 afA[4], afB[4];
  {
    const ushort* base = whhP + (long)dir * 256 * 64;
#pragma unroll
    for (int n = 0; n < 4; ++n) {
      const ushort* rp = base + (64 * w + 16 * n + s) * 64 + q * 8;
      afA[n] = *(const bf16x8*)rp;
      afB[n] = *(const bf16x8*)(rp + 32);
    }
  }

  const int b = bg * 16 + s;
  const long xgrow = ((long)dir * B_ + b) * T_;
  const int cOff = w * 128 + q * 32;  // byte offset of this lane's 16 halfs
  const int hsw = (s & 7) << 4;
  const int a0b = s * 128 + ((q * 16) ^ hsw);         // B-frag k in [0,32)
  const int a1b = s * 128 + ((64 + q * 16) ^ hsw);    // B-frag k in [32,64)
  const int wbb = s * 128 + ((32 * w + 8 * q) ^ hsw); // b64 h write (4 units)

  float cst[4] = {0.f, 0.f, 0.f, 0.f};

  uint4 xA0, xB0, xA1, xB1;
  {
    const int tt0 = dir ? (T_ - 1) : 0;
    const char* xr = (const char*)xgP + (xgrow + tt0) * 512 + cOff;
    xA0 = *(const uint4*)xr;
    xB0 = *(const uint4*)(xr + 16);
  }
  {
    const int tt1 = dir ? (T_ - 2) : 1;
    const char* xr = (const char*)xgP + (xgrow + tt1) * 512 + cOff;
    xA1 = *(const uint4*)xr;
    xB1 = *(const uint4*)(xr + 16);
  }
  __syncthreads();

  for (int it = 0; it < T_ / 2; ++it) {
    LSTM_STEP(2 * it, xA0, xB0);
    LSTM_STEP(2 * it + 1, xA1, xB1);
  }
}

// ---------------- Attention pool + LayerNorm + FC (bf16 hio) ---------------
__global__ __launch_bounds__(256) void head_kernel(
    const ushort* __restrict__ hio, const float* __restrict__ attn_w,
    const float* __restrict__ attn_b, const float* __restrict__ ln_g,
    const float* __restrict__ ln_b, const float* __restrict__ fc_w,
    const float* __restrict__ fc_b, float* __restrict__ res) {
  const int b = blockIdx.x;
  const int tid = threadIdx.x;
  __shared__ __align__(16) float aw[128];
  __shared__ float l[T_];
  __shared__ float red[16];
  __shared__ float pp[2][128];
  __shared__ float normed[128];
  if (tid < 128) aw[tid] = attn_w[tid];
  __syncthreads();
  const float ab = attn_b[0];

  for (int t = tid; t < T_; t += 256) {
    const ushort* row = hio + ((long)b * T_ + t) * 128;
    float a = ab;
#pragma unroll
    for (int d = 0; d < 128; d += 8) {
      uint4 v = *(const uint4*)(row + d);
      float2 p0 = bfpair(v.x), p1 = bfpair(v.y);
      float2 p2 = bfpair(v.z), p3 = bfpair(v.w);
      a += p0.x * aw[d] + p0.y * aw[d + 1] + p1.x * aw[d + 2] +
           p1.y * aw[d + 3] + p2.x * aw[d + 4] + p2.y * aw[d + 5] +
           p3.x * aw[d + 6] + p3.y * aw[d + 7];
    }
    l[t] = a;
  }
  __syncthreads();

  float v0 = l[tid], v1 = l[tid + 256];
  float m = fmaxf(v0, v1);
#pragma unroll
  for (int off = 32; off >= 1; off >>= 1) m = fmaxf(m, __shfl_xor(m, off));
  if ((tid & 63) == 0) red[tid >> 6] = m;
  __syncthreads();
  m = fmaxf(fmaxf(red[0], red[1]), fmaxf(red[2], red[3]));
  float e0 = __expf(v0 - m), e1 = __expf(v1 - m);
  float ssum = e0 + e1;
#pragma unroll
  for (int off = 32; off >= 1; off >>= 1) ssum += __shfl_xor(ssum, off);
  if ((tid & 63) == 0) red[4 + (tid >> 6)] = ssum;
  __syncthreads();
  float inv = 1.f / (red[4] + red[5] + red[6] + red[7]);
  l[tid] = e0 * inv;
  l[tid + 256] = e1 * inv;
  __syncthreads();

  const int d = tid & 127, half = tid >> 7;
  float p = 0.f;
  for (int t = half * 256; t < half * 256 + 256; ++t)
    p += l[t] * bf2f(hio[((long)b * T_ + t) * 128 + d]);
  pp[half][d] = p;
  __syncthreads();

  if (tid < 128) {
    float pv = pp[0][tid] + pp[1][tid];
    float s1 = pv, s2 = pv * pv;
#pragma unroll
    for (int off = 32; off >= 1; off >>= 1) {
      s1 += __shfl_xor(s1, off);
      s2 += __shfl_xor(s2, off);
    }
    if ((tid & 63) == 0) {
      red[8 + (tid >> 6) * 2] = s1;
      red[9 + (tid >> 6) * 2] = s2;
    }
  }
  __syncthreads();
  if (tid < 128) {
    float s1 = red[8] + red[10], s2 = red[9] + red[11];
    float mu = s1 * (1.f / 128.f);
    float var = s2 * (1.f / 128.f) - mu * mu;
    float rinv = rsqrtf(var + 1e-5f);
    float pv = pp[0][tid] + pp[1][tid];
    normed[tid] = (pv - mu) * rinv * ln_g[tid] + ln_b[tid];
  }
  __syncthreads();

  if (tid < 2) {
    float a = fc_b[tid];
    for (int d2 = 0; d2 < 128; ++d2) a += normed[d2] * fc_w[tid * 128 + d2];
    res[b * 2 + tid] = a;
  }
}

extern "C" void kernel_launch(void* const* d_in, const int* in_sizes, int n_in,
                              void* d_out, int out_size, void* d_ws,
                              size_t ws_size, hipStream_t stream) {
  const float* x = (const float*)d_in[0];
  const float* conv_w = (const float*)d_in[1];
  const float* conv_b = (const float*)d_in[2];
  const float* w_ih_f = (const float*)d_in[3];
  const float* w_hh_f = (const float*)d_in[4];
  const float* b_f = (const float*)d_in[5];
  const float* w_ih_b = (const float*)d_in[6];
  const float* w_hh_b = (const float*)d_in[7];
  const float* b_b = (const float*)d_in[8];
  const float* attn_w = (const float*)d_in[9];
  const float* attn_b = (const float*)d_in[10];
  const float* ln_g = (const float*)d_in[11];
  const float* ln_b = (const float*)d_in[12];
  const float* fc_w = (const float*)d_in[13];
  const float* fc_b = (const float*)d_in[14];
  float* res = (float*)d_out;

  // ws layout (~161 MiB):
  char* ws = (char*)d_ws;
  ushort* wbT = (ushort*)ws;                      // 294,912 B
  ushort* wP = (ushort*)(ws + 0x60000);           // 131,072 B
  ushort* whhP = (ushort*)(ws + 0x80000);         // 65,536 B
  float* biasP = (float*)(ws + 0x90000);          // 2,048 B
  ushort* xgP = (ushort*)(ws + 0x100000);         // 134,217,728 B
  ushort* y = (ushort*)(ws + 0x100000 + 134217728);  // 33,554,432 B
  ushort* hout = y;  // aliases y: y is dead after xg_gemm

  pack_w_kernel<<<576, 256, 0, stream>>>(conv_w, wbT);
  pack_wiP_kernel<<<256, 256, 0, stream>>>(w_ih_f, w_ih_b, wP);
  pack_whhP_kernel<<<128, 256, 0, stream>>>(w_hh_f, w_hh_b, whhP);
  pack_biasP_kernel<<<2, 256, 0, stream>>>(b_f, b_b, biasP);
  conv_gemm_kernel<<<B_ * (T_ / 128), 256, 0, stream>>>(x, wbT, conv_b, y);
  xg_gemm_kernel<<<(B_ * T_ / 128) * 4, 256, 0, stream>>>(y, wP, biasP, xgP);
  lstm_seq_kernel<<<32, 256, 0, stream>>>(whhP, xgP, hout);
  head_kernel<<<B_, 256, 0, stream>>>(hout, attn_w, attn_b, ln_g, ln_b, fc_w,
                                      fc_b, res);
}

// Round 7
// 532.041 us; speedup vs baseline: 1.2039x; 1.0496x over previous
//
#include <hip/hip_runtime.h>
#include <hip/hip_fp16.h>
#include <math.h>

typedef unsigned int uint;
typedef unsigned short ushort;

#define B_ 256
#define T_ 512
#define F_ 378
#define C_ 128
#define H_ 64
#define KPAD 1152   // 3 * 384

using f32x4 = __attribute__((ext_vector_type(4))) float;
using bf16x8 = __attribute__((ext_vector_type(8))) short;

__device__ __forceinline__ ushort f2bf(float f) {
  union { float f; uint u; } c; c.f = f;
  uint r = (c.u + 0x7fffu + ((c.u >> 16) & 1u)) >> 16;
  return (ushort)r;
}
__device__ __forceinline__ float bf2f(ushort u) {
  union { uint u; float f; } c; c.u = ((uint)u) << 16;
  return c.f;
}
__device__ __forceinline__ uint packbf2(float a, float b) {
  return (uint)f2bf(a) | (((uint)f2bf(b)) << 16);
}
__device__ __forceinline__ float2 bfpair(uint u) {
  union { uint u; float f; } a, b;
  a.u = (u & 0xffffu) << 16;
  b.u = u & 0xffff0000u;
  float2 r; r.x = a.f; r.y = b.f; return r;
}
// fast activations: v_exp_f32 is 2^x; rcp is 1-ulp-ish (fine at bf16 scale)
__device__ __forceinline__ float sigm(float v) {
  return __builtin_amdgcn_rcpf(1.f + __builtin_amdgcn_exp2f(-1.442695041f * v));
}
__device__ __forceinline__ float tanh_fast(float v) {
  return fmaf(-2.f,
              __builtin_amdgcn_rcpf(1.f + __builtin_amdgcn_exp2f(2.885390082f * v)),
              1.f);
}

// ---------------- pack conv w -> wbT[c][kk], kk = k*384+f, bf16 ------------
__global__ __launch_bounds__(256) void pack_w_kernel(
    const float* __restrict__ w, ushort* __restrict__ wbT) {
  int i = blockIdx.x * 256 + threadIdx.x;
  if (i >= C_ * KPAD) return;
  int c = i / KPAD, kk = i - c * KPAD;
  int k = kk / 384, f = kk - k * 384;
  float v = (f < F_) ? w[c * (F_ * 3) + f * 3 + k] : 0.f;
  wbT[i] = f2bf(v);
}

// ---- pack w_ih -> wP[dir][g''][128] bf16; g'' = w*64+q*16+n*4+e ----------
__global__ __launch_bounds__(256) void pack_wiP_kernel(
    const float* __restrict__ wf, const float* __restrict__ wb,
    ushort* __restrict__ wP) {
  int i = blockIdx.x * 256 + threadIdx.x;  // 2*256*128 = 65536
  int dir = i >> 15, rem = i & 32767;
  int gp = rem >> 7, k = rem & 127;
  int e = gp & 3, n = (gp >> 2) & 3, q = (gp >> 4) & 3, w = gp >> 6;
  int u = 16 * w + 4 * q + n;
  const float* src = dir ? wb : wf;
  wP[i] = f2bf(src[(e * 64 + u) * 128 + k]);
}

// ---- pack w_hh -> whhP[dir][r][64] bf16; r = 64w+16n+4q+e -----------------
__global__ __launch_bounds__(256) void pack_whhP_kernel(
    const float* __restrict__ wf, const float* __restrict__ wb,
    ushort* __restrict__ whhP) {
  int i = blockIdx.x * 256 + threadIdx.x;  // 2*256*64 = 32768
  if (i >= 32768) return;
  int dir = i >> 14, rem = i & 16383;
  int r = rem >> 6, k = rem & 63;
  int e = r & 3, q = (r >> 2) & 3, n = (r >> 4) & 3, w = r >> 6;
  int u = 16 * w + 4 * q + n;
  const float* src = dir ? wb : wf;
  whhP[i] = f2bf(src[(e * 64 + u) * 64 + k]);
}

// ---- pack bias -> biasP[dir][g''] fp32 (same order as wP) -----------------
__global__ __launch_bounds__(256) void pack_biasP_kernel(
    const float* __restrict__ bf, const float* __restrict__ bb,
    float* __restrict__ biasP) {
  int i = blockIdx.x * 256 + threadIdx.x;  // 512
  if (i >= 512) return;
  int dir = i >> 8, gp = i & 255;
  int e = gp & 3, n = (gp >> 2) & 3, q = (gp >> 4) & 3, w = gp >> 6;
  int u = 16 * w + 4 * q + n;
  const float* src = dir ? bb : bf;
  biasP[i] = src[e * 64 + u];
}

// ---------------- Conv1d as implicit GEMM, bf16 MFMA (unchanged) -----------
__global__ __launch_bounds__(256, 2) void conv_gemm_kernel(
    const float* __restrict__ x, const ushort* __restrict__ wbT,
    const float* __restrict__ bias, ushort* __restrict__ y) {
  __shared__ __align__(16) char xsb[130 * 128];
  __shared__ __align__(16) char bsb[128 * 384];
  const int tid = threadIdx.x;
  const int lane = tid & 63;
  const int wr = (tid >> 7) & 1;
  const int wc = (tid >> 6) & 1;
  const int b = blockIdx.x >> 2;
  const int t0 = (blockIdx.x & 3) << 7;

  f32x4 acc[4][4];
#pragma unroll
  for (int m = 0; m < 4; ++m)
#pragma unroll
    for (int n = 0; n < 4; ++n) acc[m][n] = (f32x4)(0.f);

  for (int fs = 0; fs < 6; ++fs) {
    __syncthreads();
    {
      auto stage_a = [&](int r, int h) {
        const int t = t0 - 1 + r;
        const bool ok = (t >= 0) && (t < T_);
        const float* srow = x + ((long)b * T_ + (ok ? t : 0)) * F_;
        const int fb = fs * 64 + h * 32;
        char* dst = xsb + r * 128;
        const int sw = (r & 7) << 4;
        uint pk[16];
        if (ok && fb + 31 < F_) {
#pragma unroll
          for (int j = 0; j < 16; ++j) {
            float2 v = *(const float2*)(srow + fb + 2 * j);
            pk[j] = packbf2(v.x, v.y);
          }
        } else {
#pragma unroll
          for (int j = 0; j < 16; ++j) {
            const int f = fb + 2 * j;
            float a = (ok && f < F_) ? srow[f] : 0.f;
            float c2 = (ok && f + 1 < F_) ? srow[f + 1] : 0.f;
            pk[j] = packbf2(a, c2);
          }
        }
#pragma unroll
        for (int j = 0; j < 4; ++j) {
          uint4 p = {pk[4 * j], pk[4 * j + 1], pk[4 * j + 2], pk[4 * j + 3]};
          *(uint4*)(dst + ((h * 64 + j * 16) ^ sw)) = p;
        }
      };
      stage_a(tid >> 1, tid & 1);
      if (tid < 4) stage_a(128 + (tid >> 1), tid & 1);
    }
    {
      const int c = tid >> 1, h = tid & 1;
      const ushort* src = wbT + c * KPAD + fs * 64 + h * 32;
      char* drow = bsb + c * 384;
      const int sw = (c & 7) << 4;
#pragma unroll
      for (int k = 0; k < 3; ++k)
#pragma unroll
        for (int j = 0; j < 4; ++j) {
          uint4 v = *(const uint4*)(src + k * 384 + j * 8);
          *(uint4*)(drow + k * 128 + ((h * 64 + j * 16) ^ sw)) = v;
        }
    }
    __syncthreads();

#pragma unroll
    for (int k = 0; k < 3; ++k) {
#pragma unroll
      for (int s = 0; s < 2; ++s) {
        bf16x8 af[4], bfx[4];
        const int ksub = s * 64 + ((lane >> 4) << 4);
#pragma unroll
        for (int m = 0; m < 4; ++m) {
          const int rr = wr * 64 + m * 16 + (lane & 15) + k;
          af[m] = *(const bf16x8*)(xsb + rr * 128 + (ksub ^ ((rr & 7) << 4)));
        }
#pragma unroll
        for (int n = 0; n < 4; ++n) {
          const int c = wc * 64 + n * 16 + (lane & 15);
          bfx[n] =
              *(const bf16x8*)(bsb + c * 384 + k * 128 + (ksub ^ ((c & 7) << 4)));
        }
#pragma unroll
        for (int m = 0; m < 4; ++m)
#pragma unroll
          for (int n = 0; n < 4; ++n)
            acc[m][n] = __builtin_amdgcn_mfma_f32_16x16x32_bf16(
                af[m], bfx[n], acc[m][n], 0, 0, 0);
      }
    }
  }

  __syncthreads();
  float bc[4];
#pragma unroll
  for (int n = 0; n < 4; ++n) bc[n] = bias[wc * 64 + n * 16 + (lane & 15)];
#pragma unroll
  for (int m = 0; m < 4; ++m) {
#pragma unroll
    for (int n = 0; n < 4; ++n) {
      const int col = wc * 64 + n * 16 + (lane & 15);
#pragma unroll
      for (int r = 0; r < 4; ++r) {
        const int row = wr * 64 + m * 16 + ((lane >> 4) << 2) + r;
        float v = acc[m][n][r] + bc[n];
        v = v > 0.f ? v : 0.f;
        *(ushort*)(bsb + row * 256 + ((col * 2) ^ ((row & 7) << 4))) = f2bf(v);
      }
    }
  }
  __syncthreads();
  const int w = tid >> 6;
#pragma unroll
  for (int p = 0; p < 8; ++p) {
    const int rowb = p * 16 + w * 4 + (lane >> 4);
    const int colb = (lane & 15) * 16;
    uint4 v = *(const uint4*)(bsb + rowb * 256 + (colb ^ ((rowb & 7) << 4)));
    *(uint4*)((char*)(y + ((long)b * T_ + t0 + rowb) * 128) + colb) = v;
  }
}

// ---------------- xg GEMM: xgP[dir][b*T+t][256] fp16 = y @ wP^T + bias -----
__global__ __launch_bounds__(256, 2) void xg_gemm_kernel(
    const ushort* __restrict__ y, const ushort* __restrict__ wP,
    const float* __restrict__ biasP, ushort* __restrict__ xgP) {
  __shared__ __align__(16) char xsb[128 * 256];
  __shared__ __align__(16) char bsb[128 * 256];
  const int tid = threadIdx.x;
  const int lane = tid & 63;
  const int wr = (tid >> 7) & 1;
  const int wc = (tid >> 6) & 1;
  const int mb = blockIdx.x >> 2;
  const int nb = blockIdx.x & 3;
  const int m0 = mb << 7;
  const int dirBT = (nb >> 1) * (B_ * T_);
  const int gbase = (nb >> 1) * 256 + (nb & 1) * 128;

  {
    const int r = tid >> 1, h = tid & 1;
    const int sw = (r & 7) << 4;
    const ushort* sa = y + ((long)(m0 + r)) * 128 + h * 64;
    const ushort* sb = wP + (gbase + r) * 128 + h * 64;
    char* da = xsb + r * 256;
    char* db = bsb + r * 256;
#pragma unroll
    for (int j = 0; j < 8; ++j) {
      uint4 va = *(const uint4*)(sa + 8 * j);
      uint4 vb = *(const uint4*)(sb + 8 * j);
      const int inner = (h * 128 + j * 16) ^ sw;
      *(uint4*)(da + inner) = va;
      *(uint4*)(db + inner) = vb;
    }
  }
  __syncthreads();

  f32x4 acc[4][4];
#pragma unroll
  for (int m = 0; m < 4; ++m)
#pragma unroll
    for (int n = 0; n < 4; ++n) acc[m][n] = (f32x4)(0.f);

#pragma unroll
  for (int ks = 0; ks < 4; ++ks) {
    bf16x8 af[4], bfx[4];
    const int ksub = ks * 64 + ((lane >> 4) << 4);
#pragma unroll
    for (int m = 0; m < 4; ++m) {
      const int rr = wr * 64 + m * 16 + (lane & 15);
      af[m] = *(const bf16x8*)(xsb + rr * 256 + (ksub ^ ((rr & 7) << 4)));
    }
#pragma unroll
    for (int n = 0; n < 4; ++n) {
      const int c = wc * 64 + n * 16 + (lane & 15);
      bfx[n] = *(const bf16x8*)(bsb + c * 256 + (ksub ^ ((c & 7) << 4)));
    }
#pragma unroll
    for (int m = 0; m < 4; ++m)
#pragma unroll
      for (int n = 0; n < 4; ++n)
        acc[m][n] = __builtin_amdgcn_mfma_f32_16x16x32_bf16(af[m], bfx[n],
                                                            acc[m][n], 0, 0, 0);
  }

  __syncthreads();
  float bc[4];
#pragma unroll
  for (int n = 0; n < 4; ++n)
    bc[n] = biasP[gbase + wc * 64 + n * 16 + (lane & 15)];
#pragma unroll
  for (int m = 0; m < 4; ++m) {
#pragma unroll
    for (int n = 0; n < 4; ++n) {
      const int col = wc * 64 + n * 16 + (lane & 15);
#pragma unroll
      for (int r = 0; r < 4; ++r) {
        const int row = wr * 64 + m * 16 + ((lane >> 4) << 2) + r;
        float v = acc[m][n][r] + bc[n];
        __half hv = __float2half(v);
        *(ushort*)(bsb + row * 256 + ((col * 2) ^ ((row & 7) << 4))) =
            *(ushort*)&hv;
      }
    }
  }
  __syncthreads();
  const int w = tid >> 6;
#pragma unroll
  for (int p = 0; p < 8; ++p) {
    const int rowb = p * 16 + w * 4 + (lane >> 4);
    const int colb = (lane & 15) * 16;
    uint4 v = *(const uint4*)(bsb + rowb * 256 + (colb ^ ((rowb & 7) << 4)));
    *(uint4*)((char*)xgP + ((long)(dirBT + m0 + rowb)) * 512 + (nb & 1) * 256 +
              colb) = v;
  }
}

// ---------------- LSTM scan: 16 seqs/block, 4 waves, MFMA recurrence -------
// BRANCH-FREE loop: 32 phases x 16 fully-unrolled steps + unconditional
// flush. xg prefetched 8 steps deep in registers (static slot indices) so
// the compiler emits counted vmcnt (loads stay in flight across barriers)
// instead of a per-step vmcnt(0) HBM drain (the R5 step cost ~1805cy; the
// conditional flush branch broke waitcnt tracking).
#define LSTM_STEP16(J)                                                         \
  do {                                                                         \
    const int t_ = t0ph + (J);                                                 \
    const int p_ = (J) & 1;                                                    \
    const uint4 curA = xA[(J) & 7], curB = xB[(J) & 7];                        \
    {                                                                          \
      int tp = t_ + 8;                                                         \
      tp = tp > T_ - 1 ? T_ - 1 : tp;                                          \
      const int ttp = dir ? (T_ - 1 - tp) : tp;                                \
      const char* xr = (const char*)xgP + (xgrow + ttp) * 512 + cOff;          \
      xA[(J) & 7] = *(const uint4*)xr;                                         \
      xB[(J) & 7] = *(const uint4*)(xr + 16);                                  \
    }                                                                          \
    bf16x8 bh0, bh1, bl0, bl1;                                                 \
    {                                                                          \
      const char* hb = (const char*)hhi + p_ * 2048;                           \
      const char* lb = (const char*)hlo + p_ * 2048;                           \
      bh0 = *(const bf16x8*)(hb + a0b);                                        \
      bh1 = *(const bf16x8*)(hb + a1b);                                        \
      bl0 = *(const bf16x8*)(lb + a0b);                                        \
      bl1 = *(const bf16x8*)(lb + a1b);                                        \
    }                                                                          \
    f32x4 acH[4], acL[4];                                                      \
    _Pragma("unroll") for (int n = 0; n < 4; ++n) {                            \
      acH[n] = __builtin_amdgcn_mfma_f32_16x16x32_bf16(afA[n], bh0,            \
                                                       (f32x4)(0.f), 0, 0, 0); \
      acL[n] = __builtin_amdgcn_mfma_f32_16x16x32_bf16(afA[n], bl0,            \
                                                       (f32x4)(0.f), 0, 0, 0); \
    }                                                                          \
    _Pragma("unroll") for (int n = 0; n < 4; ++n) {                            \
      acH[n] =                                                                 \
          __builtin_amdgcn_mfma_f32_16x16x32_bf16(afB[n], bh1, acH[n], 0, 0, 0); \
      acL[n] =                                                                 \
          __builtin_amdgcn_mfma_f32_16x16x32_bf16(afB[n], bl1, acL[n], 0, 0, 0); \
    }                                                                          \
    ushort hiu[4];                                                             \
    float hv[4];                                                               \
    _Pragma("unroll") for (int n = 0; n < 4; ++n) {                            \
      const uint lo32 = (n & 1) ? ((n & 2) ? curB.z : curA.z)                  \
                                : ((n & 2) ? curB.x : curA.x);                 \
      const uint hi32 = (n & 1) ? ((n & 2) ? curB.w : curA.w)                  \
                                : ((n & 2) ? curB.y : curA.y);                 \
      float2 x01 = __half22float2(*(const __half2*)&lo32);                     \
      float2 x23 = __half22float2(*(const __half2*)&hi32);                     \
      float pi = acH[n][0] + acL[n][0] + x01.x;                                \
      float pf = acH[n][1] + acL[n][1] + x01.y;                                \
      float pg = acH[n][2] + acL[n][2] + x23.x;                                \
      float po = acH[n][3] + acL[n][3] + x23.y;                                \
      cst[n] = sigm(pf) * cst[n] + sigm(pi) * tanh_fast(pg);                   \
      hv[n] = sigm(po) * tanh_fast(cst[n]);                                    \
      hiu[n] = f2bf(hv[n]);                                                    \
    }                                                                          \
    {                                                                          \
      uint2 HV, LV;                                                            \
      HV.x = (uint)hiu[0] | ((uint)hiu[1] << 16);                              \
      HV.y = (uint)hiu[2] | ((uint)hiu[3] << 16);                              \
      LV.x = (uint)f2bf(hv[0] - bf2f(hiu[0])) |                                \
             ((uint)f2bf(hv[1] - bf2f(hiu[1])) << 16);                         \
      LV.y = (uint)f2bf(hv[2] - bf2f(hiu[2])) |                                \
             ((uint)f2bf(hv[3] - bf2f(hiu[3])) << 16);                         \
      *(uint2*)((char*)hhi + (1 - p_) * 2048 + wbb) = HV;                      \
      *(uint2*)((char*)hlo + (1 - p_) * 2048 + wbb) = LV;                      \
      *(uint2*)((char*)hstage + stbase + (J) * 2048 + wbb) = HV;               \
    }                                                                          \
    if ((J) == 15) {                                                           \
      asm volatile("s_waitcnt lgkmcnt(0)" ::: "memory");                       \
    } else {                                                                   \
      asm volatile("s_waitcnt lgkmcnt(1)" ::: "memory");                       \
    }                                                                          \
    __builtin_amdgcn_sched_barrier(0);                                         \
    __builtin_amdgcn_s_barrier();                                              \
    __builtin_amdgcn_sched_barrier(0);                                         \
  } while (0)

__global__ __launch_bounds__(256, 1) void lstm_seq_kernel(
    const ushort* __restrict__ whhP, const ushort* __restrict__ xgP,
    ushort* __restrict__ hout) {
  const int dir = blockIdx.x >> 4;
  const int bg = blockIdx.x & 15;
  const int tid = threadIdx.x;
  const int lane = tid & 63;
  const int w = tid >> 6;   // wave 0..3
  const int s = lane & 15;  // sequence within group
  const int q = lane >> 4;  // quarter

  __shared__ __align__(16) ushort hhi[2 * 1024];        // [2][16s][64u]
  __shared__ __align__(16) ushort hlo[2 * 1024];
  __shared__ __align__(16) ushort hstage[2 * 16 * 16 * 64];  // 64KB

  for (int i = tid; i < 2048; i += 256) {
    hhi[i] = 0;
    hlo[i] = 0;
  }

  // pinned A-frags: whhP rows 64w+16n+s, k chunks [0,32),[32,64)
  bf16x8 afA[4], afB[4];
  {
    const ushort* base = whhP + (long)dir * 256 * 64;
#pragma unroll
    for (int n = 0; n < 4; ++n) {
      const ushort* rp = base + (64 * w + 16 * n + s) * 64 + q * 8;
      afA[n] = *(const bf16x8*)rp;
      afB[n] = *(const bf16x8*)(rp + 32);
    }
  }

  const int b = bg * 16 + s;
  const long xgrow = ((long)dir * B_ + b) * T_;
  const int cOff = w * 128 + q * 32;  // byte offset of this lane's 16 halfs
  const int hsw = (s & 7) << 4;
  const int a0b = s * 128 + ((q * 16) ^ hsw);         // B-frag k in [0,32)
  const int a1b = s * 128 + ((64 + q * 16) ^ hsw);    // B-frag k in [32,64)
  const int wbb = s * 128 + ((32 * w + 8 * q) ^ hsw); // b64 h write (4 units)

  float cst[4] = {0.f, 0.f, 0.f, 0.f};

  // 8-deep register prefetch of xg (32B/step/lane)
  uint4 xA[8], xB[8];
#pragma unroll
  for (int j = 0; j < 8; ++j) {
    const int tt = dir ? (T_ - 1 - j) : j;
    const char* xr = (const char*)xgP + (xgrow + tt) * 512 + cOff;
    xA[j] = *(const uint4*)xr;
    xB[j] = *(const uint4*)(xr + 16);
  }
  __syncthreads();

  for (int ph = 0; ph < 32; ++ph) {
    const int t0ph = ph * 16;
    const int stbase = (ph & 1) * 32768;
    LSTM_STEP16(0);
    LSTM_STEP16(1);
    LSTM_STEP16(2);
    LSTM_STEP16(3);
    LSTM_STEP16(4);
    LSTM_STEP16(5);
    LSTM_STEP16(6);
    LSTM_STEP16(7);
    LSTM_STEP16(8);
    LSTM_STEP16(9);
    LSTM_STEP16(10);
    LSTM_STEP16(11);
    LSTM_STEP16(12);
    LSTM_STEP16(13);
    LSTM_STEP16(14);
    LSTM_STEP16(15);
    // ---- unconditional flush of 16 steps of h (straight-line, no branch) --
    {
      const int ftl = tid >> 4, fs = tid & 15;
      const int fsw = (fs & 7) << 4;
      const char* sb2 = (const char*)hstage + stbase + ftl * 2048 + fs * 128;
      const int st_ = t0ph + ftl;
      const int gt = dir ? (T_ - 1 - st_) : st_;
      ushort* dst = hout + ((long)(bg * 16 + fs) * T_ + gt) * 128 + dir * 64;
#pragma unroll
      for (int j2 = 0; j2 < 8; ++j2) {
        uint4 v = *(const uint4*)(sb2 + ((j2 * 16) ^ fsw));
        *(uint4*)(dst + j2 * 8) = v;
      }
    }
  }
}

// ---------------- Attention pool + LayerNorm + FC (bf16 hio) ---------------
__global__ __launch_bounds__(256) void head_kernel(
    const ushort* __restrict__ hio, const float* __restrict__ attn_w,
    const float* __restrict__ attn_b, const float* __restrict__ ln_g,
    const float* __restrict__ ln_b, const float* __restrict__ fc_w,
    const float* __restrict__ fc_b, float* __restrict__ res) {
  const int b = blockIdx.x;
  const int tid = threadIdx.x;
  __shared__ __align__(16) float aw[128];
  __shared__ float l[T_];
  __shared__ float red[16];
  __shared__ float pp[2][128];
  __shared__ float normed[128];
  if (tid < 128) aw[tid] = attn_w[tid];
  __syncthreads();
  const float ab = attn_b[0];

  for (int t = tid; t < T_; t += 256) {
    const ushort* row = hio + ((long)b * T_ + t) * 128;
    float a = ab;
#pragma unroll
    for (int d = 0; d < 128; d += 8) {
      uint4 v = *(const uint4*)(row + d);
      float2 p0 = bfpair(v.x), p1 = bfpair(v.y);
      float2 p2 = bfpair(v.z), p3 = bfpair(v.w);
      a += p0.x * aw[d] + p0.y * aw[d + 1] + p1.x * aw[d + 2] +
           p1.y * aw[d + 3] + p2.x * aw[d + 4] + p2.y * aw[d + 5] +
           p3.x * aw[d + 6] + p3.y * aw[d + 7];
    }
    l[t] = a;
  }
  __syncthreads();

  float v0 = l[tid], v1 = l[tid + 256];
  float m = fmaxf(v0, v1);
#pragma unroll
  for (int off = 32; off >= 1; off >>= 1) m = fmaxf(m, __shfl_xor(m, off));
  if ((tid & 63) == 0) red[tid >> 6] = m;
  __syncthreads();
  m = fmaxf(fmaxf(red[0], red[1]), fmaxf(red[2], red[3]));
  float e0 = __expf(v0 - m), e1 = __expf(v1 - m);
  float ssum = e0 + e1;
#pragma unroll
  for (int off = 32; off >= 1; off >>= 1) ssum += __shfl_xor(ssum, off);
  if ((tid & 63) == 0) red[4 + (tid >> 6)] = ssum;
  __syncthreads();
  float inv = 1.f / (red[4] + red[5] + red[6] + red[7]);
  l[tid] = e0 * inv;
  l[tid + 256] = e1 * inv;
  __syncthreads();

  const int d = tid & 127, half = tid >> 7;
  float p = 0.f;
  for (int t = half * 256; t < half * 256 + 256; ++t)
    p += l[t] * bf2f(hio[((long)b * T_ + t) * 128 + d]);
  pp[half][d] = p;
  __syncthreads();

  if (tid < 128) {
    float pv = pp[0][tid] + pp[1][tid];
    float s1 = pv, s2 = pv * pv;
#pragma unroll
    for (int off = 32; off >= 1; off >>= 1) {
      s1 += __shfl_xor(s1, off);
      s2 += __shfl_xor(s2, off);
    }
    if ((tid & 63) == 0) {
      red[8 + (tid >> 6) * 2] = s1;
      red[9 + (tid >> 6) * 2] = s2;
    }
  }
  __syncthreads();
  if (tid < 128) {
    float s1 = red[8] + red[10], s2 = red[9] + red[11];
    float mu = s1 * (1.f / 128.f);
    float var = s2 * (1.f / 128.f) - mu * mu;
    float rinv = rsqrtf(var + 1e-5f);
    float pv = pp[0][tid] + pp[1][tid];
    normed[tid] = (pv - mu) * rinv * ln_g[tid] + ln_b[tid];
  }
  __syncthreads();

  if (tid < 2) {
    float a = fc_b[tid];
    for (int d2 = 0; d2 < 128; ++d2) a += normed[d2] * fc_w[tid * 128 + d2];
    res[b * 2 + tid] = a;
  }
}

extern "C" void kernel_launch(void* const* d_in, const int* in_sizes, int n_in,
                              void* d_out, int out_size, void* d_ws,
                              size_t ws_size, hipStream_t stream) {
  const float* x = (const float*)d_in[0];
  const float* conv_w = (const float*)d_in[1];
  const float* conv_b = (const float*)d_in[2];
  const float* w_ih_f = (const float*)d_in[3];
  const float* w_hh_f = (const float*)d_in[4];
  const float* b_f = (const float*)d_in[5];
  const float* w_ih_b = (const float*)d_in[6];
  const float* w_hh_b = (const float*)d_in[7];
  const float* b_b = (const float*)d_in[8];
  const float* attn_w = (const float*)d_in[9];
  const float* attn_b = (const float*)d_in[10];
  const float* ln_g = (const float*)d_in[11];
  const float* ln_b = (const float*)d_in[12];
  const float* fc_w = (const float*)d_in[13];
  const float* fc_b = (const float*)d_in[14];
  float* res = (float*)d_out;

  // ws layout (~161 MiB):
  char* ws = (char*)d_ws;
  ushort* wbT = (ushort*)ws;                      // 294,912 B
  ushort* wP = (ushort*)(ws + 0x60000);           // 131,072 B
  ushort* whhP = (ushort*)(ws + 0x80000);         // 65,536 B
  float* biasP = (float*)(ws + 0x90000);          // 2,048 B
  ushort* xgP = (ushort*)(ws + 0x100000);         // 134,217,728 B
  ushort* y = (ushort*)(ws + 0x100000 + 134217728);  // 33,554,432 B
  ushort* hout = y;  // aliases y: y is dead after xg_gemm

  pack_w_kernel<<<576, 256, 0, stream>>>(conv_w, wbT);
  pack_wiP_kernel<<<256, 256, 0, stream>>>(w_ih_f, w_ih_b, wP);
  pack_whhP_kernel<<<128, 256, 0, stream>>>(w_hh_f, w_hh_b, whhP);
  pack_biasP_kernel<<<2, 256, 0, stream>>>(b_f, b_b, biasP);
  conv_gemm_kernel<<<B_ * (T_ / 128), 256, 0, stream>>>(x, wbT, conv_b, y);
  xg_gemm_kernel<<<(B_ * T_ / 128) * 4, 256, 0, stream>>>(y, wP, biasP, xgP);
  lstm_seq_kernel<<<32, 256, 0, stream>>>(whhP, xgP, hout);
  head_kernel<<<B_, 256, 0, stream>>>(hout, attn_w, attn_b, ln_g, ln_b, fc_w,
                                      fc_b, res);
}

// Round 8
// 459.572 us; speedup vs baseline: 1.3937x; 1.1577x over previous
//
#include <hip/hip_runtime.h>
#include <hip/hip_fp16.h>
#include <math.h>

typedef unsigned int uint;
typedef unsigned short ushort;

#define B_ 256
#define T_ 512
#define F_ 378
#define C_ 128
#define H_ 64
#define KPAD 1152   // 3 * 384

using f32x4 = __attribute__((ext_vector_type(4))) float;
using bf16x8 = __attribute__((ext_vector_type(8))) short;
using f16x8 = __attribute__((ext_vector_type(8))) _Float16;

__device__ __forceinline__ ushort f2bf(float f) {
  union { float f; uint u; } c; c.f = f;
  uint r = (c.u + 0x7fffu + ((c.u >> 16) & 1u)) >> 16;
  return (ushort)r;
}
__device__ __forceinline__ float bf2f(ushort u) {
  union { uint u; float f; } c; c.u = ((uint)u) << 16;
  return c.f;
}
__device__ __forceinline__ uint packbf2(float a, float b) {
  return (uint)f2bf(a) | (((uint)f2bf(b)) << 16);
}
__device__ __forceinline__ ushort f2h(float f) {
  __half h = __float2half(f);
  return *(ushort*)&h;
}
__device__ __forceinline__ float h2f(ushort u) {
  __half h;
  *(ushort*)&h = u;
  return __half2float(h);
}
// fast activations: v_exp_f32 is 2^x; rcp is 1-ulp-ish (fine at bf16 scale)
__device__ __forceinline__ float sigm(float v) {
  return __builtin_amdgcn_rcpf(1.f + __builtin_amdgcn_exp2f(-1.442695041f * v));
}
__device__ __forceinline__ float tanh_fast(float v) {
  return fmaf(-2.f,
              __builtin_amdgcn_rcpf(1.f + __builtin_amdgcn_exp2f(2.885390082f * v)),
              1.f);
}

// ---------------- pack conv w -> wbT[c][kk], kk = k*384+f, bf16 ------------
__global__ __launch_bounds__(256) void pack_w_kernel(
    const float* __restrict__ w, ushort* __restrict__ wbT) {
  int i = blockIdx.x * 256 + threadIdx.x;
  if (i >= C_ * KPAD) return;
  int c = i / KPAD, kk = i - c * KPAD;
  int k = kk / 384, f = kk - k * 384;
  float v = (f < F_) ? w[c * (F_ * 3) + f * 3 + k] : 0.f;
  wbT[i] = f2bf(v);
}

// ---- pack w_ih -> wP[dir][g''][128] bf16; g'' = w*64+q*16+n*4+e ----------
__global__ __launch_bounds__(256) void pack_wiP_kernel(
    const float* __restrict__ wf, const float* __restrict__ wb,
    ushort* __restrict__ wP) {
  int i = blockIdx.x * 256 + threadIdx.x;  // 2*256*128 = 65536
  int dir = i >> 15, rem = i & 32767;
  int gp = rem >> 7, k = rem & 127;
  int e = gp & 3, n = (gp >> 2) & 3, q = (gp >> 4) & 3, w = gp >> 6;
  int u = 16 * w + 4 * q + n;
  const float* src = dir ? wb : wf;
  wP[i] = f2bf(src[(e * 64 + u) * 128 + k]);
}

// ---- pack w_hh -> whhP[dir][r][64] FP16; r = 64w+16n+4q+e -----------------
// (fp16, not bf16: |w_hh| < 1 so fp16's 11-bit mantissa is ~exact; the scan
// uses mfma_f32_16x16x32_f16 with fp16 h feedback - single path, no hi/lo.)
__global__ __launch_bounds__(256) void pack_whhP_kernel(
    const float* __restrict__ wf, const float* __restrict__ wb,
    ushort* __restrict__ whhP) {
  int i = blockIdx.x * 256 + threadIdx.x;  // 2*256*64 = 32768
  if (i >= 32768) return;
  int dir = i >> 14, rem = i & 16383;
  int r = rem >> 6, k = rem & 63;
  int e = r & 3, q = (r >> 2) & 3, n = (r >> 4) & 3, w = r >> 6;
  int u = 16 * w + 4 * q + n;
  const float* src = dir ? wb : wf;
  whhP[i] = f2h(src[(e * 64 + u) * 64 + k]);
}

// ---- pack bias -> biasP[dir][g''] fp32 (same order as wP) -----------------
__global__ __launch_bounds__(256) void pack_biasP_kernel(
    const float* __restrict__ bf, const float* __restrict__ bb,
    float* __restrict__ biasP) {
  int i = blockIdx.x * 256 + threadIdx.x;  // 512
  if (i >= 512) return;
  int dir = i >> 8, gp = i & 255;
  int e = gp & 3, n = (gp >> 2) & 3, q = (gp >> 4) & 3, w = gp >> 6;
  int u = 16 * w + 4 * q + n;
  const float* src = dir ? bb : bf;
  biasP[i] = src[e * 64 + u];
}

// ---------------- Conv1d as implicit GEMM, bf16 MFMA (unchanged) -----------
__global__ __launch_bounds__(256, 2) void conv_gemm_kernel(
    const float* __restrict__ x, const ushort* __restrict__ wbT,
    const float* __restrict__ bias, ushort* __restrict__ y) {
  __shared__ __align__(16) char xsb[130 * 128];
  __shared__ __align__(16) char bsb[128 * 384];
  const int tid = threadIdx.x;
  const int lane = tid & 63;
  const int wr = (tid >> 7) & 1;
  const int wc = (tid >> 6) & 1;
  const int b = blockIdx.x >> 2;
  const int t0 = (blockIdx.x & 3) << 7;

  f32x4 acc[4][4];
#pragma unroll
  for (int m = 0; m < 4; ++m)
#pragma unroll
    for (int n = 0; n < 4; ++n) acc[m][n] = (f32x4)(0.f);

  for (int fs = 0; fs < 6; ++fs) {
    __syncthreads();
    {
      auto stage_a = [&](int r, int h) {
        const int t = t0 - 1 + r;
        const bool ok = (t >= 0) && (t < T_);
        const float* srow = x + ((long)b * T_ + (ok ? t : 0)) * F_;
        const int fb = fs * 64 + h * 32;
        char* dst = xsb + r * 128;
        const int sw = (r & 7) << 4;
        uint pk[16];
        if (ok && fb + 31 < F_) {
#pragma unroll
          for (int j = 0; j < 16; ++j) {
            float2 v = *(const float2*)(srow + fb + 2 * j);
            pk[j] = packbf2(v.x, v.y);
          }
        } else {
#pragma unroll
          for (int j = 0; j < 16; ++j) {
            const int f = fb + 2 * j;
            float a = (ok && f < F_) ? srow[f] : 0.f;
            float c2 = (ok && f + 1 < F_) ? srow[f + 1] : 0.f;
            pk[j] = packbf2(a, c2);
          }
        }
#pragma unroll
        for (int j = 0; j < 4; ++j) {
          uint4 p = {pk[4 * j], pk[4 * j + 1], pk[4 * j + 2], pk[4 * j + 3]};
          *(uint4*)(dst + ((h * 64 + j * 16) ^ sw)) = p;
        }
      };
      stage_a(tid >> 1, tid & 1);
      if (tid < 4) stage_a(128 + (tid >> 1), tid & 1);
    }
    {
      const int c = tid >> 1, h = tid & 1;
      const ushort* src = wbT + c * KPAD + fs * 64 + h * 32;
      char* drow = bsb + c * 384;
      const int sw = (c & 7) << 4;
#pragma unroll
      for (int k = 0; k < 3; ++k)
#pragma unroll
        for (int j = 0; j < 4; ++j) {
          uint4 v = *(const uint4*)(src + k * 384 + j * 8);
          *(uint4*)(drow + k * 128 + ((h * 64 + j * 16) ^ sw)) = v;
        }
    }
    __syncthreads();

#pragma unroll
    for (int k = 0; k < 3; ++k) {
#pragma unroll
      for (int s = 0; s < 2; ++s) {
        bf16x8 af[4], bfx[4];
        const int ksub = s * 64 + ((lane >> 4) << 4);
#pragma unroll
        for (int m = 0; m < 4; ++m) {
          const int rr = wr * 64 + m * 16 + (lane & 15) + k;
          af[m] = *(const bf16x8*)(xsb + rr * 128 + (ksub ^ ((rr & 7) << 4)));
        }
#pragma unroll
        for (int n = 0; n < 4; ++n) {
          const int c = wc * 64 + n * 16 + (lane & 15);
          bfx[n] =
              *(const bf16x8*)(bsb + c * 384 + k * 128 + (ksub ^ ((c & 7) << 4)));
        }
#pragma unroll
        for (int m = 0; m < 4; ++m)
#pragma unroll
          for (int n = 0; n < 4; ++n)
            acc[m][n] = __builtin_amdgcn_mfma_f32_16x16x32_bf16(
                af[m], bfx[n], acc[m][n], 0, 0, 0);
      }
    }
  }

  __syncthreads();
  float bc[4];
#pragma unroll
  for (int n = 0; n < 4; ++n) bc[n] = bias[wc * 64 + n * 16 + (lane & 15)];
#pragma unroll
  for (int m = 0; m < 4; ++m) {
#pragma unroll
    for (int n = 0; n < 4; ++n) {
      const int col = wc * 64 + n * 16 + (lane & 15);
#pragma unroll
      for (int r = 0; r < 4; ++r) {
        const int row = wr * 64 + m * 16 + ((lane >> 4) << 2) + r;
        float v = acc[m][n][r] + bc[n];
        v = v > 0.f ? v : 0.f;
        *(ushort*)(bsb + row * 256 + ((col * 2) ^ ((row & 7) << 4))) = f2bf(v);
      }
    }
  }
  __syncthreads();
  const int w = tid >> 6;
#pragma unroll
  for (int p = 0; p < 8; ++p) {
    const int rowb = p * 16 + w * 4 + (lane >> 4);
    const int colb = (lane & 15) * 16;
    uint4 v = *(const uint4*)(bsb + rowb * 256 + (colb ^ ((rowb & 7) << 4)));
    *(uint4*)((char*)(y + ((long)b * T_ + t0 + rowb) * 128) + colb) = v;
  }
}

// ---------------- xg GEMM: xgP[dir][b*T+t][256] fp16 = y @ wP^T + bias -----
__global__ __launch_bounds__(256, 2) void xg_gemm_kernel(
    const ushort* __restrict__ y, const ushort* __restrict__ wP,
    const float* __restrict__ biasP, ushort* __restrict__ xgP) {
  __shared__ __align__(16) char xsb[128 * 256];
  __shared__ __align__(16) char bsb[128 * 256];
  const int tid = threadIdx.x;
  const int lane = tid & 63;
  const int wr = (tid >> 7) & 1;
  const int wc = (tid >> 6) & 1;
  const int mb = blockIdx.x >> 2;
  const int nb = blockIdx.x & 3;
  const int m0 = mb << 7;
  const int dirBT = (nb >> 1) * (B_ * T_);
  const int gbase = (nb >> 1) * 256 + (nb & 1) * 128;

  {
    const int r = tid >> 1, h = tid & 1;
    const int sw = (r & 7) << 4;
    const ushort* sa = y + ((long)(m0 + r)) * 128 + h * 64;
    const ushort* sb = wP + (gbase + r) * 128 + h * 64;
    char* da = xsb + r * 256;
    char* db = bsb + r * 256;
#pragma unroll
    for (int j = 0; j < 8; ++j) {
      uint4 va = *(const uint4*)(sa + 8 * j);
      uint4 vb = *(const uint4*)(sb + 8 * j);
      const int inner = (h * 128 + j * 16) ^ sw;
      *(uint4*)(da + inner) = va;
      *(uint4*)(db + inner) = vb;
    }
  }
  __syncthreads();

  f32x4 acc[4][4];
#pragma unroll
  for (int m = 0; m < 4; ++m)
#pragma unroll
    for (int n = 0; n < 4; ++n) acc[m][n] = (f32x4)(0.f);

#pragma unroll
  for (int ks = 0; ks < 4; ++ks) {
    bf16x8 af[4], bfx[4];
    const int ksub = ks * 64 + ((lane >> 4) << 4);
#pragma unroll
    for (int m = 0; m < 4; ++m) {
      const int rr = wr * 64 + m * 16 + (lane & 15);
      af[m] = *(const bf16x8*)(xsb + rr * 256 + (ksub ^ ((rr & 7) << 4)));
    }
#pragma unroll
    for (int n = 0; n < 4; ++n) {
      const int c = wc * 64 + n * 16 + (lane & 15);
      bfx[n] = *(const bf16x8*)(bsb + c * 256 + (ksub ^ ((c & 7) << 4)));
    }
#pragma unroll
    for (int m = 0; m < 4; ++m)
#pragma unroll
      for (int n = 0; n < 4; ++n)
        acc[m][n] = __builtin_amdgcn_mfma_f32_16x16x32_bf16(af[m], bfx[n],
                                                            acc[m][n], 0, 0, 0);
  }

  __syncthreads();
  float bc[4];
#pragma unroll
  for (int n = 0; n < 4; ++n)
    bc[n] = biasP[gbase + wc * 64 + n * 16 + (lane & 15)];
#pragma unroll
  for (int m = 0; m < 4; ++m) {
#pragma unroll
    for (int n = 0; n < 4; ++n) {
      const int col = wc * 64 + n * 16 + (lane & 15);
#pragma unroll
      for (int r = 0; r < 4; ++r) {
        const int row = wr * 64 + m * 16 + ((lane >> 4) << 2) + r;
        float v = acc[m][n][r] + bc[n];
        *(ushort*)(bsb + row * 256 + ((col * 2) ^ ((row & 7) << 4))) = f2h(v);
      }
    }
  }
  __syncthreads();
  const int w = tid >> 6;
#pragma unroll
  for (int p = 0; p < 8; ++p) {
    const int rowb = p * 16 + w * 4 + (lane >> 4);
    const int colb = (lane & 15) * 16;
    uint4 v = *(const uint4*)(bsb + rowb * 256 + (colb ^ ((rowb & 7) << 4)));
    *(uint4*)((char*)xgP + ((long)(dirBT + m0 + rowb)) * 512 + (nb & 1) * 256 +
              colb) = v;
  }
}

// ---------------- LSTM scan: 16 seqs/block, 4 waves, fp16 MFMA recurrence --
// Single fp16 h path (no hi/lo): per step per wave = 2 ds_read_b128 ->
// 8 independent MFMA (2/tile, scalar join) -> nonlin -> 1 ds_write_b64 +
// fire-and-forget global b64 h store -> lgkmcnt(0) -> barrier. hstage/flush
// machinery deleted (h goes straight to HBM; stores never waited on).
#define LSTM_STEP8(J)                                                          \
  do {                                                                         \
    const int t_ = t0ph + (J);                                                 \
    const int p_ = (J) & 1;                                                    \
    const uint4 curA = xA[(J)], curB = xB[(J)];                                \
    {                                                                          \
      int tp = t_ + 8;                                                         \
      tp = tp > T_ - 1 ? T_ - 1 : tp;                                          \
      const int ttp = dir ? (T_ - 1 - tp) : tp;                                \
      const char* xr = (const char*)xgP + (xgrow + ttp) * 512 + cOff;          \
      xA[(J)] = *(const uint4*)xr;                                             \
      xB[(J)] = *(const uint4*)(xr + 16);                                      \
    }                                                                          \
    f16x8 bh0, bh1;                                                            \
    {                                                                          \
      const char* hb = (const char*)hbuf + p_ * 2048;                          \
      bh0 = *(const f16x8*)(hb + a0b);                                         \
      bh1 = *(const f16x8*)(hb + a1b);                                         \
    }                                                                          \
    ushort hu[4];                                                              \
    _Pragma("unroll") for (int n = 0; n < 4; ++n) {                            \
      f32x4 ac0 = __builtin_amdgcn_mfma_f32_16x16x32_f16(afA[n], bh0,          \
                                                         (f32x4)(0.f), 0, 0, 0); \
      f32x4 ac1 = __builtin_amdgcn_mfma_f32_16x16x32_f16(afB[n], bh1,          \
                                                         (f32x4)(0.f), 0, 0, 0); \
      const uint lo32 = (n & 1) ? ((n & 2) ? curB.z : curA.z)                  \
                                : ((n & 2) ? curB.x : curA.x);                 \
      const uint hi32 = (n & 1) ? ((n & 2) ? curB.w : curA.w)                  \
                                : ((n & 2) ? curB.y : curA.y);                 \
      float2 x01 = __half22float2(*(const __half2*)&lo32);                     \
      float2 x23 = __half22float2(*(const __half2*)&hi32);                     \
      float pi = ac0[0] + ac1[0] + x01.x;                                      \
      float pf = ac0[1] + ac1[1] + x01.y;                                      \
      float pg = ac0[2] + ac1[2] + x23.x;                                      \
      float po = ac0[3] + ac1[3] + x23.y;                                      \
      cst[n] = sigm(pf) * cst[n] + sigm(pi) * tanh_fast(pg);                   \
      hu[n] = f2h(sigm(po) * tanh_fast(cst[n]));                               \
    }                                                                          \
    {                                                                          \
      uint2 HV;                                                                \
      HV.x = (uint)hu[0] | ((uint)hu[1] << 16);                                \
      HV.y = (uint)hu[2] | ((uint)hu[3] << 16);                                \
      *(uint2*)((char*)hbuf + (1 - p_) * 2048 + wbb) = HV;                     \
      const int gt = dir ? (T_ - 1 - t_) : t_;                                 \
      *(uint2*)(houtRow + (long)gt * 128) = HV;                                \
    }                                                                          \
    asm volatile("s_waitcnt lgkmcnt(0)" ::: "memory");                         \
    __builtin_amdgcn_sched_barrier(0);                                         \
    __builtin_amdgcn_s_barrier();                                              \
    __builtin_amdgcn_sched_barrier(0);                                         \
  } while (0)

__global__ __launch_bounds__(256, 1) void lstm_seq_kernel(
    const ushort* __restrict__ whhP, const ushort* __restrict__ xgP,
    ushort* __restrict__ hout) {
  const int dir = blockIdx.x >> 4;
  const int bg = blockIdx.x & 15;
  const int tid = threadIdx.x;
  const int lane = tid & 63;
  const int w = tid >> 6;   // wave 0..3
  const int s = lane & 15;  // sequence within group
  const int q = lane >> 4;  // quarter

  __shared__ __align__(16) ushort hbuf[2 * 1024];  // [2][16s][64u] fp16

  for (int i = tid; i < 2048; i += 256) hbuf[i] = 0;

  // pinned A-frags (fp16): whhP rows 64w+16n+s, k chunks [0,32),[32,64)
  f16x8 afA[4], afB[4];
  {
    const ushort* base = whhP + (long)dir * 256 * 64;
#pragma unroll
    for (int n = 0; n < 4; ++n) {
      const ushort* rp = base + (64 * w + 16 * n + s) * 64 + q * 8;
      afA[n] = *(const f16x8*)rp;
      afB[n] = *(const f16x8*)(rp + 32);
    }
  }

  const int b = bg * 16 + s;
  const long xgrow = ((long)dir * B_ + b) * T_;
  const int cOff = w * 128 + q * 32;  // byte offset of this lane's 16 halfs
  const int hsw = (s & 7) << 4;
  const int a0b = s * 128 + ((q * 16) ^ hsw);         // B-frag k in [0,32)
  const int a1b = s * 128 + ((64 + q * 16) ^ hsw);    // B-frag k in [32,64)
  const int wbb = s * 128 + ((32 * w + 8 * q) ^ hsw); // b64 h write (4 units)
  ushort* houtRow = hout + (long)b * T_ * 128 + dir * 64 + 16 * w + 4 * q;

  float cst[4] = {0.f, 0.f, 0.f, 0.f};

  // 8-deep register prefetch of xg (32B/step/lane)
  uint4 xA[8], xB[8];
#pragma unroll
  for (int j = 0; j < 8; ++j) {
    const int tt = dir ? (T_ - 1 - j) : j;
    const char* xr = (const char*)xgP + (xgrow + tt) * 512 + cOff;
    xA[j] = *(const uint4*)xr;
    xB[j] = *(const uint4*)(xr + 16);
  }
  __syncthreads();

  for (int ph = 0; ph < 64; ++ph) {
    const int t0ph = ph * 8;
    LSTM_STEP8(0);
    LSTM_STEP8(1);
    LSTM_STEP8(2);
    LSTM_STEP8(3);
    LSTM_STEP8(4);
    LSTM_STEP8(5);
    LSTM_STEP8(6);
    LSTM_STEP8(7);
  }
}

// ---------------- Attention pool + LayerNorm + FC (fp16 hio) ---------------
__global__ __launch_bounds__(256) void head_kernel(
    const ushort* __restrict__ hio, const float* __restrict__ attn_w,
    const float* __restrict__ attn_b, const float* __restrict__ ln_g,
    const float* __restrict__ ln_b, const float* __restrict__ fc_w,
    const float* __restrict__ fc_b, float* __restrict__ res) {
  const int b = blockIdx.x;
  const int tid = threadIdx.x;
  __shared__ __align__(16) float aw[128];
  __shared__ float l[T_];
  __shared__ float red[16];
  __shared__ float pp[2][128];
  __shared__ float normed[128];
  if (tid < 128) aw[tid] = attn_w[tid];
  __syncthreads();
  const float ab = attn_b[0];

  for (int t = tid; t < T_; t += 256) {
    const ushort* row = hio + ((long)b * T_ + t) * 128;
    float a = ab;
#pragma unroll
    for (int d = 0; d < 128; d += 8) {
      uint4 v = *(const uint4*)(row + d);
      float2 p0 = __half22float2(*(const __half2*)&v.x);
      float2 p1 = __half22float2(*(const __half2*)&v.y);
      float2 p2 = __half22float2(*(const __half2*)&v.z);
      float2 p3 = __half22float2(*(const __half2*)&v.w);
      a += p0.x * aw[d] + p0.y * aw[d + 1] + p1.x * aw[d + 2] +
           p1.y * aw[d + 3] + p2.x * aw[d + 4] + p2.y * aw[d + 5] +
           p3.x * aw[d + 6] + p3.y * aw[d + 7];
    }
    l[t] = a;
  }
  __syncthreads();

  float v0 = l[tid], v1 = l[tid + 256];
  float m = fmaxf(v0, v1);
#pragma unroll
  for (int off = 32; off >= 1; off >>= 1) m = fmaxf(m, __shfl_xor(m, off));
  if ((tid & 63) == 0) red[tid >> 6] = m;
  __syncthreads();
  m = fmaxf(fmaxf(red[0], red[1]), fmaxf(red[2], red[3]));
  float e0 = __expf(v0 - m), e1 = __expf(v1 - m);
  float ssum = e0 + e1;
#pragma unroll
  for (int off = 32; off >= 1; off >>= 1) ssum += __shfl_xor(ssum, off);
  if ((tid & 63) == 0) red[4 + (tid >> 6)] = ssum;
  __syncthreads();
  float inv = 1.f / (red[4] + red[5] + red[6] + red[7]);
  l[tid] = e0 * inv;
  l[tid + 256] = e1 * inv;
  __syncthreads();

  const int d = tid & 127, half = tid >> 7;
  float p = 0.f;
  for (int t = half * 256; t < half * 256 + 256; ++t)
    p += l[t] * h2f(hio[((long)b * T_ + t) * 128 + d]);
  pp[half][d] = p;
  __syncthreads();

  if (tid < 128) {
    float pv = pp[0][tid] + pp[1][tid];
    float s1 = pv, s2 = pv * pv;
#pragma unroll
    for (int off = 32; off >= 1; off >>= 1) {
      s1 += __shfl_xor(s1, off);
      s2 += __shfl_xor(s2, off);
    }
    if ((tid & 63) == 0) {
      red[8 + (tid >> 6) * 2] = s1;
      red[9 + (tid >> 6) * 2] = s2;
    }
  }
  __syncthreads();
  if (tid < 128) {
    float s1 = red[8] + red[10], s2 = red[9] + red[11];
    float mu = s1 * (1.f / 128.f);
    float var = s2 * (1.f / 128.f) - mu * mu;
    float rinv = rsqrtf(var + 1e-5f);
    float pv = pp[0][tid] + pp[1][tid];
    normed[tid] = (pv - mu) * rinv * ln_g[tid] + ln_b[tid];
  }
  __syncthreads();

  if (tid < 2) {
    float a = fc_b[tid];
    for (int d2 = 0; d2 < 128; ++d2) a += normed[d2] * fc_w[tid * 128 + d2];
    res[b * 2 + tid] = a;
  }
}

extern "C" void kernel_launch(void* const* d_in, const int* in_sizes, int n_in,
                              void* d_out, int out_size, void* d_ws,
                              size_t ws_size, hipStream_t stream) {
  const float* x = (const float*)d_in[0];
  const float* conv_w = (const float*)d_in[1];
  const float* conv_b = (const float*)d_in[2];
  const float* w_ih_f = (const float*)d_in[3];
  const float* w_hh_f = (const float*)d_in[4];
  const float* b_f = (const float*)d_in[5];
  const float* w_ih_b = (const float*)d_in[6];
  const float* w_hh_b = (const float*)d_in[7];
  const float* b_b = (const float*)d_in[8];
  const float* attn_w = (const float*)d_in[9];
  const float* attn_b = (const float*)d_in[10];
  const float* ln_g = (const float*)d_in[11];
  const float* ln_b = (const float*)d_in[12];
  const float* fc_w = (const float*)d_in[13];
  const float* fc_b = (const float*)d_in[14];
  float* res = (float*)d_out;

  // ws layout (~161 MiB):
  char* ws = (char*)d_ws;
  ushort* wbT = (ushort*)ws;                      // 294,912 B
  ushort* wP = (ushort*)(ws + 0x60000);           // 131,072 B
  ushort* whhP = (ushort*)(ws + 0x80000);         // 65,536 B (fp16)
  float* biasP = (float*)(ws + 0x90000);          // 2,048 B
  ushort* xgP = (ushort*)(ws + 0x100000);         // 134,217,728 B (fp16)
  ushort* y = (ushort*)(ws + 0x100000 + 134217728);  // 33,554,432 B
  ushort* hout = y;  // aliases y (fp16 now): y is dead after xg_gemm

  pack_w_kernel<<<576, 256, 0, stream>>>(conv_w, wbT);
  pack_wiP_kernel<<<256, 256, 0, stream>>>(w_ih_f, w_ih_b, wP);
  pack_whhP_kernel<<<128, 256, 0, stream>>>(w_hh_f, w_hh_b, whhP);
  pack_biasP_kernel<<<2, 256, 0, stream>>>(b_f, b_b, biasP);
  conv_gemm_kernel<<<B_ * (T_ / 128), 256, 0, stream>>>(x, wbT, conv_b, y);
  xg_gemm_kernel<<<(B_ * T_ / 128) * 4, 256, 0, stream>>>(y, wP, biasP, xgP);
  lstm_seq_kernel<<<32, 256, 0, stream>>>(whhP, xgP, hout);
  head_kernel<<<B_, 256, 0, stream>>>(hout, attn_w, attn_b, ln_g, ln_b, fc_w,
                                      fc_b, res);
}